// Round 10
// baseline (738.229 us; speedup 1.0000x reference)
//
#include <hip/hip_runtime.h>
#include <cstdint>
#include <cstddef>

#define DN 128
#define NND 50000
#define NED 512000
#define NSCAN 49   // ceil(NND/1024)

typedef __attribute__((ext_vector_type(8))) short bf8;
typedef __attribute__((ext_vector_type(4))) float f4;
typedef unsigned short us;

__device__ __forceinline__ us f2bf(float f){
  union { float f; unsigned int u; } c; c.f = f;
  unsigned int r = c.u + 0x7fffu + ((c.u >> 16) & 1u);
  return (us)(r >> 16);
}
__device__ __forceinline__ float bf2f(us u){
  union { unsigned int u; float f; } c; c.u = ((unsigned int)u) << 16;
  return c.f;
}
// mish(x) = x*tanh(softplus(x)) = x*(u^2-1)/(u^2+1), u = 1+exp(x)
// fast divide: (u2-1)*rcp(u2+1) — bf16-output precision is unaffected.
__device__ __forceinline__ float mishf(float x){
  float e = __expf(x);
  float u = 1.f + e;
  float u2 = u * u;
  float t = __fdividef(u2 - 1.f, u2 + 1.f);
  return x * ((x > 20.f) ? 1.f : t);
}

#define MFMA16(a, b, c) __builtin_amdgcn_mfma_f32_16x16x32_bf16((a), (b), (c), 0, 0, 0)

// LDS fragment read: row-major [rows][K=128] bf16 with (row&7)<<4 byte XOR swizzle.
__device__ __forceinline__ bf8 lds_frag(const us* base, int row, int kElem){
  int byte = row * 256 + kElem * 2;
  byte ^= (row & 7) << 4;
  return *(const bf8*)((const char*)base + byte);
}
// Global weight fragment: W^T stored [Nout][K] bf16, plain row-major.
__device__ __forceinline__ bf8 gfrag(const us* W, int n, int K, int kElem){
  return *(const bf8*)(W + (size_t)n * K + kElem);
}

// ======== wave-local 32-row x 128-col primitives (zero cross-wave sync) ========
// Wave tile T: 32 rows x 128 cols bf16 (8KB, swizzled). acc[rt][ct][reg]:
// row = rt*16 + g*4 + reg, col = ct*16 + s. A-frags a[rt][kk]: row rt*16+s,
// k = kk*32 + g*8. B loaded once per (ct,kk) -> 2x MFMA reuse.

__device__ __forceinline__ void loadA32(const us* T, int g, int s, bf8 (&a)[2][4]){
#pragma unroll
  for (int rt = 0; rt < 2; ++rt)
#pragma unroll
    for (int kk = 0; kk < 4; ++kk)
      a[rt][kk] = lds_frag(T, rt*16 + s, kk*32 + g*8);
}

__device__ __forceinline__ void gemm32(const bf8 (&a)[2][4], const us* __restrict__ WT,
                                       int K, int kOff, const float* __restrict__ bias,
                                       bool init, int g, int s, f4 (&acc)[2][8]){
  if (init){
#pragma unroll
    for (int ct = 0; ct < 8; ++ct){
      float bv = bias ? bias[ct*16 + s] : 0.f;
      f4 t = {bv, bv, bv, bv};
      acc[0][ct] = t; acc[1][ct] = t;
    }
  }
#pragma unroll
  for (int ct = 0; ct < 8; ++ct){
    int n = ct*16 + s;
#pragma unroll
    for (int kk = 0; kk < 4; ++kk){
      bf8 b = gfrag(WT, n, K, kOff + kk*32 + g*8);
      acc[0][ct] = MFMA16(a[0][kk], b, acc[0][ct]);
      acc[1][ct] = MFMA16(a[1][kk], b, acc[1][ct]);
    }
  }
}

// LayerNorm over the 128-wide row fully in-wave + mish.
__device__ __forceinline__ void ln_mish32(f4 (&acc)[2][8],
                                          const float* __restrict__ gam,
                                          const float* __restrict__ bet, int s){
#pragma unroll
  for (int rt = 0; rt < 2; ++rt){
    float mu[4], rs[4];
#pragma unroll
    for (int reg = 0; reg < 4; ++reg){
      float sm = 0.f, sq = 0.f;
#pragma unroll
      for (int ct = 0; ct < 8; ++ct){ float v = acc[rt][ct][reg]; sm += v; sq += v*v; }
#pragma unroll
      for (int m = 1; m < 16; m <<= 1){ sm += __shfl_xor(sm, m, 64); sq += __shfl_xor(sq, m, 64); }
      float mm = sm * (1.f/128.f);
      float var = sq * (1.f/128.f) - mm*mm;
      mu[reg] = mm; rs[reg] = rsqrtf(var + 1e-5f);
    }
#pragma unroll
    for (int ct = 0; ct < 8; ++ct){
      float gv = gam[ct*16 + s], bv = bet[ct*16 + s];
#pragma unroll
      for (int reg = 0; reg < 4; ++reg)
        acc[rt][ct][reg] = mishf((acc[rt][ct][reg] - mu[reg]) * rs[reg] * gv + bv);
    }
  }
}

__device__ __forceinline__ void mish32(f4 (&acc)[2][8]){
#pragma unroll
  for (int rt = 0; rt < 2; ++rt)
#pragma unroll
    for (int ct = 0; ct < 8; ++ct)
#pragma unroll
      for (int reg = 0; reg < 4; ++reg)
        acc[rt][ct][reg] = mishf(acc[rt][ct][reg]);
}

__device__ __forceinline__ void writeT32(us* T, int g, int s, const f4 (&A)[2][8]){
#pragma unroll
  for (int rt = 0; rt < 2; ++rt)
#pragma unroll
    for (int ct = 0; ct < 8; ++ct)
#pragma unroll
      for (int reg = 0; reg < 4; ++reg){
        int row = rt*16 + g*4 + reg, col = ct*16 + s;
        int byte = row*256 + col*2; byte ^= (row & 7) << 4;
        *(us*)((char*)T + byte) = f2bf(A[rt][ct][reg]);
      }
}

template<int OUT_BF16>
__device__ __forceinline__ void store32(void* outp, int row0, int g, int s, int ostride,
                                        const f4 (&A)[2][8]){
#pragma unroll
  for (int rt = 0; rt < 2; ++rt)
#pragma unroll
    for (int ct = 0; ct < 8; ++ct)
#pragma unroll
      for (int reg = 0; reg < 4; ++reg){
        int row = row0 + rt*16 + g*4 + reg;
        if (row < NND){
          int col = ct*16 + s;
          if constexpr (OUT_BF16 != 0)
            ((us*)outp)[(size_t)row*ostride + col] = f2bf(A[rt][ct][reg]);
          else
            ((float*)outp)[(size_t)row*ostride + col] = A[rt][ct][reg];
        }
      }
}

// stage 16 rows (row-half hh) of a f32 [*,128] matrix into T as bf16, 4 lanes/row
__device__ __forceinline__ void stageF32(us* T, const float* __restrict__ src,
                                         int row0, int hh, int r, int c4, int ostride){
  int grow = row0 + hh*16 + r; if (grow >= NND) grow = NND - 1;
  const f4* sp = (const f4*)(src + (size_t)grow * ostride + c4 * 32);
  int lrow = hh*16 + r;
#pragma unroll
  for (int j = 0; j < 4; ++j){
    f4 v0 = sp[2*j], v1 = sp[2*j+1];
    bf8 o;
#pragma unroll
    for (int q = 0; q < 4; ++q){ o[q] = (short)f2bf(v0[q]); o[4+q] = (short)f2bf(v1[q]); }
    int byte = lrow*256 + c4*64 + j*16; byte ^= (lrow & 7) << 4;
    *(bf8*)((char*)T + byte) = o;
  }
}

// ---------- Fused node chains: 2-wave blocks, 32-row waves, barrier-free ----------
__global__ __launch_bounds__(128)
void node_fused(const float* __restrict__ X,
                const us* __restrict__ WqT,  const float* __restrict__ bq,
                const float* __restrict__ gq, const float* __restrict__ beq,
                const us* __restrict__ WkT,  const float* __restrict__ bk,
                const float* __restrict__ gk, const float* __restrict__ bek,
                const us* __restrict__ Wm1T, const float* __restrict__ bm1,
                const float* __restrict__ gm, const float* __restrict__ bem,
                const us* __restrict__ Wm2T, const float* __restrict__ bm2,
                const us* __restrict__ Wb1T, const float* __restrict__ bb1,
                const float* __restrict__ gb, const float* __restrict__ beb,
                const us* __restrict__ Wb2T, const float* __restrict__ bb2,
                const us* __restrict__ Wc1T, const float* __restrict__ bc1,
                const us* __restrict__ Wc2T,
                us* __restrict__ qt, us* __restrict__ kmb, float* __restrict__ xout)
{
  __shared__ us Tsh[2][32 * DN];   // 8KB per wave

  const int tid = threadIdx.x;
  const int lane = tid & 63, w = tid >> 6;
  const int g = lane >> 4, s = lane & 15;
  const int r = lane >> 2, c4 = lane & 3;
  const int row0 = blockIdx.x * 64 + w * 32;
  us* T = (us*)Tsh[w];

  stageF32(T, X, row0, 0, r, c4, DN);
  stageF32(T, X, row0, 1, r, c4, DN);

  bf8 a[2][4], a2[2][4];
  loadA32(T, g, s, a);       // X frags live across all 5 chains
  f4 acc[2][8];

  // ---- q ----
  gemm32(a, WqT, DN, 0, bq, true, g, s, acc);
  ln_mish32(acc, gq, beq, s);
  store32<1>((void*)qt, row0, g, s, DN, acc);

  // ---- k ----
  gemm32(a, WkT, DN, 0, bk, true, g, s, acc);
  ln_mish32(acc, gk, bek, s);
  store32<1>((void*)kmb, row0, g, s, 384, acc);

  // ---- m (2 GEMM) ----
  gemm32(a, Wm1T, DN, 0, bm1, true, g, s, acc);
  ln_mish32(acc, gm, bem, s);
  writeT32(T, g, s, acc);
  loadA32(T, g, s, a2);
  gemm32(a2, Wm2T, DN, 0, bm2, true, g, s, acc);
  store32<1>((void*)(kmb + 128), row0, g, s, 384, acc);

  // ---- b (2 GEMM) ----
  gemm32(a, Wb1T, DN, 0, bb1, true, g, s, acc);
  ln_mish32(acc, gb, beb, s);
  writeT32(T, g, s, acc);
  loadA32(T, g, s, a2);
  gemm32(a2, Wb2T, DN, 0, bb2, true, g, s, acc);
  store32<1>((void*)(kmb + 256), row0, g, s, 384, acc);

  // ---- c (2 GEMM, no LN) ----
  gemm32(a, Wc1T, DN, 0, bc1, true, g, s, acc);
  mish32(acc);
  writeT32(T, g, s, acc);
  loadA32(T, g, s, a2);
  gemm32(a2, Wc2T, DN, 0, nullptr, true, g, s, acc);
  store32<0>((void*)xout, row0, g, s, DN, acc);
}

// ---------- CSR build ----------
__global__ void csr_count(const int* __restrict__ dst, int* __restrict__ deg){
  int e = blockIdx.x * 256 + threadIdx.x;
  if (e < NED) atomicAdd(&deg[dst[e]], 1);
}

__global__ __launch_bounds__(1024) void csr_blocksum(const int* __restrict__ deg,
                                                     int* __restrict__ bsum){
  __shared__ int sb[1024];
  int t = threadIdx.x, idx = blockIdx.x * 1024 + t;
  sb[t] = (idx < NND) ? deg[idx] : 0;
  __syncthreads();
  for (int off = 512; off > 0; off >>= 1){
    if (t < off) sb[t] += sb[t + off];
    __syncthreads();
  }
  if (t == 0) bsum[blockIdx.x] = sb[0];
}

__global__ void csr_scanroot(const int* __restrict__ bsum, int* __restrict__ boff){
  if (threadIdx.x == 0){
    int run = 0;
    for (int b = 0; b < NSCAN; ++b){ boff[b] = run; run += bsum[b]; }
  }
}

__global__ __launch_bounds__(1024) void csr_scatter(const int* __restrict__ deg,
                                                    const int* __restrict__ boff,
                                                    int* __restrict__ fillctr){
  __shared__ int ss[1024];
  int t = threadIdx.x, idx = blockIdx.x * 1024 + t;
  int v = (idx < NND) ? deg[idx] : 0;
  ss[t] = v;
  __syncthreads();
  for (int off = 1; off < 1024; off <<= 1){
    int x = (t >= off) ? ss[t - off] : 0;
    __syncthreads();
    ss[t] += x;
    __syncthreads();
  }
  if (idx < NND){
    int p = boff[blockIdx.x] + ss[t] - v;
    fillctr[idx] = p;
  }
}

__global__ void csr_fill(const int* __restrict__ src, const int* __restrict__ dst,
                         int* __restrict__ fillctr,
                         int* __restrict__ ssorted, int* __restrict__ dsorted){
  int e = blockIdx.x * 256 + threadIdx.x;
  if (e < NED){
    int d = dst[e];
    int p = atomicAdd(&fillctr[d], 1);
    ssorted[p] = src[e];
    dsorted[p] = d;
  }
}

// ---------- Edge pass: 2-wave blocks, 32 sorted edges per wave, zero barriers,
// 2x B-reuse, wave-local segment-sum. ----------
__global__ __launch_bounds__(128)
void edge_kernel(const us* __restrict__ qtab,
                 const us* __restrict__ kmb,   // [N][384]: k|m|b
                 const us* __restrict__ W1T,
                 const us* __restrict__ W2T,
                 const float* __restrict__ bw1,
                 const float* __restrict__ gwp,
                 const float* __restrict__ bewp,
                 const float* __restrict__ bw2,
                 const int* __restrict__ ssorted,
                 const int* __restrict__ dsorted,
                 float* __restrict__ hacc,      // [N][128] f32, atomic accumulate
                 float* __restrict__ colsum16)  // [16][128] f32 slices
{
  __shared__ us Tsh[2][32 * DN];   // per-wave tile: rel -> t -> p
  __shared__ int dsh[2][32];

  const int tid = threadIdx.x;
  const int lane = tid & 63, w = tid >> 6;
  const int g = lane >> 4, s = lane & 15;
  const int r = lane >> 2, c4 = lane & 3;

  // XCD-chunked swizzle (concurrent blocks cover a narrow sorted window)
  const int nchunk = gridDim.x >> 3;
  const int swz = (blockIdx.x & 7) * nchunk + (blockIdx.x >> 3);
  const int e0w = swz * 64 + w * 32;
  us* T = (us*)Tsh[w];
  int* dloc = dsh[w];

  // gather + rel for 32 edges, two 16-row halves (staging regs reused)
#pragma unroll
  for (int hh = 0; hh < 2; ++hh){
    int e = e0w + hh*16 + r;
    int sn = ssorted[e], dn = dsorted[e];
    const bf8* qp = (const bf8*)(qtab + (size_t)sn * DN + c4 * 32);
    const us*  kb = kmb + (size_t)dn * 384 + c4 * 32;
    bf8 qv[4], kv[4], mv[4], bv[4];
#pragma unroll
    for (int j = 0; j < 4; ++j){
      qv[j] = qp[j];
      kv[j] = *(const bf8*)(kb + j*8);
      mv[j] = *(const bf8*)(kb + 128 + j*8);
      bv[j] = *(const bf8*)(kb + 256 + j*8);
    }
    if (c4 == 0) dloc[hh*16 + r] = dn;

    float ss = 0.f;
#pragma unroll
    for (int j = 0; j < 4; ++j)
#pragma unroll
      for (int q = 0; q < 8; ++q){
        float d = bf2f((us)qv[j][q]) - bf2f((us)kv[j][q]);
        ss += d * d;
      }
    ss += __shfl_xor(ss, 1, 64);
    ss += __shfl_xor(ss, 2, 64);
    float rinv = rsqrtf(ss + 1e-8f);

    int lrow = hh*16 + r;
#pragma unroll
    for (int j = 0; j < 4; ++j){
      bf8 o;
#pragma unroll
      for (int q = 0; q < 8; ++q){
        float d = bf2f((us)qv[j][q]) - bf2f((us)kv[j][q]);
        float v = d * rinv * bf2f((us)mv[j][q]) + bf2f((us)bv[j][q]);
        o[q] = (short)f2bf(v);
      }
      int byte = lrow*256 + c4*64 + j*16; byte ^= (lrow & 7) << 4;
      *(bf8*)((char*)T + byte) = o;
    }
  }

  // GEMM1 -> in-wave LN+mish -> GEMM2 (acc reused) -> exp
  bf8 a[2][4];
  loadA32(T, g, s, a);
  f4 acc[2][8];
  gemm32(a, W1T, DN, 0, bw1, true, g, s, acc);
  ln_mish32(acc, gwp, bewp, s);
  writeT32(T, g, s, acc);
  bf8 a2[2][4];
  loadA32(T, g, s, a2);
  gemm32(a2, W2T, DN, 0, bw2, true, g, s, acc);
#pragma unroll
  for (int rt = 0; rt < 2; ++rt)
#pragma unroll
    for (int ct = 0; ct < 8; ++ct)
#pragma unroll
      for (int reg = 0; reg < 4; ++reg)
        acc[rt][ct][reg] = __expf(acc[rt][ct][reg]);

  // p -> wave tile (in-wave LDS ordering; no barrier needed)
  writeT32(T, g, s, acc);

  { // wave-local segment-sum: lane owns cols (2*lane, 2*lane+1), walks 32 sorted rows
    int cA = lane * 2;
    float run0 = 0.f, run1 = 0.f, cs0 = 0.f, cs1 = 0.f;
    int prev = dloc[0];
#pragma unroll 8
    for (int r2 = 0; r2 < 32; ++r2){
      int byte = r2*256 + cA*2; byte ^= (r2 & 7) << 4;
      unsigned int v = *(const unsigned int*)((const char*)T + byte);
      float f0 = bf2f((us)(v & 0xffffu));
      float f1 = bf2f((us)(v >> 16));
      int d = dloc[r2];
      cs0 += f0; cs1 += f1;
      if (d != prev){
        atomicAdd(&hacc[(size_t)prev * DN + cA], run0);
        atomicAdd(&hacc[(size_t)prev * DN + cA + 1], run1);
        run0 = f0; run1 = f1; prev = d;
      } else {
        run0 += f0; run1 += f1;
      }
    }
    atomicAdd(&hacc[(size_t)prev * DN + cA], run0);
    atomicAdd(&hacc[(size_t)prev * DN + cA + 1], run1);
    int slice = ((blockIdx.x & 7) << 1) | w;
    atomicAdd(&colsum16[slice * DN + cA], cs0);
    atomicAdd(&colsum16[slice * DN + cA + 1], cs1);
  }
}

// ---------- prep Wn1^T with 1/colsum absorbed into rows 128..255 ----------
__global__ __launch_bounds__(256)
void prep_wn1(const float* __restrict__ Wn1, const float* __restrict__ colsum16,
              us* __restrict__ wt){
  __shared__ float rcsh[DN];
  int tid = threadIdx.x;
  if (tid < DN){
    float ssum = 0.f;
#pragma unroll
    for (int x = 0; x < 16; ++x) ssum += colsum16[x * DN + tid];
    rcsh[tid] = 1.f / ssum;
  }
  __syncthreads();
  int idx = blockIdx.x * 256 + tid;     // 128 blocks x 256 = 32768 = 128n x 256k
  int n = idx >> 8, k = idx & 255;
  float v = Wn1[(size_t)k * DN + n];
  if (k >= 128) v *= rcsh[k - 128];
  wt[idx] = f2bf(v);
}

// ---------- final: h = mish(concat[node_feat, hacc] @ Wn1'(rcs-absorbed) + bn1) @ Wn2 + bn2 ----------
// 2-wave blocks, 32-row waves, barrier-free; K=256 GEMM as two staged K-halves.
__global__ __launch_bounds__(128)
void final_h(const float* __restrict__ nodef,
             const float* __restrict__ hacc,
             const us* __restrict__ Wn1T,    // [n][256], rows 128.. pre-scaled by rcs
             const float* __restrict__ bn1,
             const us* __restrict__ Wn2T,
             const float* __restrict__ bn2,
             float* __restrict__ outh)
{
  __shared__ us Tsh[2][32 * DN];

  const int tid = threadIdx.x;
  const int lane = tid & 63, w = tid >> 6;
  const int g = lane >> 4, s = lane & 15;
  const int r = lane >> 2, c4 = lane & 3;
  const int row0 = blockIdx.x * 64 + w * 32;
  us* T = (us*)Tsh[w];

  bf8 a[2][4];
  f4 acc[2][8];

  // K-half 0: node_feat
  stageF32(T, nodef, row0, 0, r, c4, DN);
  stageF32(T, nodef, row0, 1, r, c4, DN);
  loadA32(T, g, s, a);
  gemm32(a, Wn1T, 256, 0, bn1, true, g, s, acc);

  // K-half 1: hacc (raw; rcs absorbed into Wn1T)
  stageF32(T, hacc, row0, 0, r, c4, DN);
  stageF32(T, hacc, row0, 1, r, c4, DN);
  loadA32(T, g, s, a);
  gemm32(a, Wn1T, 256, 128, nullptr, false, g, s, acc);

  mish32(acc);
  writeT32(T, g, s, acc);
  loadA32(T, g, s, a);
  gemm32(a, Wn2T, DN, 0, bn2, true, g, s, acc);
  store32<0>((void*)outh, row0, g, s, DN, acc);
}

struct WPrepArgs {
  const float* w[12];
  us* wt[12];
};

// W^T bf16 (K=128): wt[n*128 + k] = bf16(W[k*128 + n])
__global__ void prep_weights(WPrepArgs a){
  int widx = blockIdx.y;
  int idx = blockIdx.x * 256 + threadIdx.x;   // 64 blocks x 256 = 16384
  int n = idx >> 7;
  int k = idx & 127;
  a.wt[widx][idx] = f2bf(a.w[widx][(size_t)k * DN + n]);
}

extern "C" void kernel_launch(void* const* d_in, const int* in_sizes, int n_in,
                              void* d_out, int out_size, void* d_ws, size_t ws_size,
                              hipStream_t stream) {
  const float* node_feat = (const float*)d_in[0];
  const float* coordf    = (const float*)d_in[1];
  const float* Wq  = (const float*)d_in[2];
  const float* bq  = (const float*)d_in[3];
  const float* gq  = (const float*)d_in[4];
  const float* beq = (const float*)d_in[5];
  const float* Wk  = (const float*)d_in[6];
  const float* bk  = (const float*)d_in[7];
  const float* gk  = (const float*)d_in[8];
  const float* bek = (const float*)d_in[9];
  const float* Wm1 = (const float*)d_in[10];
  const float* bm1 = (const float*)d_in[11];
  const float* gm  = (const float*)d_in[12];
  const float* bem = (const float*)d_in[13];
  const float* Wm2 = (const float*)d_in[14];
  const float* bm2 = (const float*)d_in[15];
  const float* Wb1 = (const float*)d_in[16];
  const float* bb1 = (const float*)d_in[17];
  const float* gb  = (const float*)d_in[18];
  const float* beb = (const float*)d_in[19];
  const float* Wb2 = (const float*)d_in[20];
  const float* bb2 = (const float*)d_in[21];
  const float* Ww1 = (const float*)d_in[22];
  const float* bw1 = (const float*)d_in[23];
  const float* gw  = (const float*)d_in[24];
  const float* bew = (const float*)d_in[25];
  const float* Ww2 = (const float*)d_in[26];
  const float* bw2 = (const float*)d_in[27];
  const float* Wn1 = (const float*)d_in[28];
  const float* bn1 = (const float*)d_in[29];
  const float* Wn2 = (const float*)d_in[30];
  const float* bn2 = (const float*)d_in[31];
  const float* Wc1 = (const float*)d_in[32];
  const float* bc1 = (const float*)d_in[33];
  const float* Wc2 = (const float*)d_in[34];
  const int* srcI  = (const int*)d_in[35];
  const int* dstI  = (const int*)d_in[36];

  char* ws = (char*)d_ws;
  size_t off = 0;
  auto alloc = [&](size_t bytes) -> char* {
    char* p = ws + off;
    off += (bytes + 255) & ~(size_t)255;
    return p;
  };
  us*    qt       = (us*)alloc((size_t)NND * DN * 2);
  us*    kmb      = (us*)alloc((size_t)NND * 384 * 2);
  float* hacc     = (float*)alloc((size_t)NND * DN * 4);
  float* colsum16 = (float*)alloc(16 * DN * 4);
  int*   deg      = (int*)alloc((size_t)NND * 4);
  int*   fillctr  = (int*)alloc((size_t)NND * 4);
  int*   ssorted  = (int*)alloc((size_t)NED * 4);
  int*   dsorted  = (int*)alloc((size_t)NED * 4);
  int*   bsum     = (int*)alloc((size_t)NSCAN * 4);
  int*   boff     = (int*)alloc((size_t)NSCAN * 4);
  us*    wtb      = (us*)alloc((size_t)13 * 16384 * 2);   // 11 K=128 + 1 K=256 (2 slots)

  // zero the atomic accumulators (hacc + colsum16 are adjacent)
  hipMemsetAsync(hacc, 0, (size_t)NND * DN * 4 + 16 * DN * 4, stream);
  hipMemsetAsync(deg, 0, (size_t)NND * 4, stream);

  WPrepArgs pa;
  const float* wsrc[11] = {Wq, Wk, Wm1, Wm2, Wb1, Wb2, Ww1, Ww2, Wc1, Wc2, Wn2};
  for (int i = 0; i < 11; ++i){
    pa.w[i] = wsrc[i];
    pa.wt[i] = wtb + (size_t)i * 16384;
  }
  us* Wn1T = wtb + (size_t)11 * 16384;   // occupies slots 11+12 (32768 us)
  prep_weights<<<dim3(64, 11), 256, 0, stream>>>(pa);

  // CSR positions + edge sort by dst
  csr_count<<<(NED + 255) / 256, 256, 0, stream>>>(dstI, deg);
  csr_blocksum<<<NSCAN, 1024, 0, stream>>>(deg, bsum);
  csr_scanroot<<<1, 64, 0, stream>>>(bsum, boff);
  csr_scatter<<<NSCAN, 1024, 0, stream>>>(deg, boff, fillctr);
  csr_fill<<<(NED + 255) / 256, 256, 0, stream>>>(srcI, dstI, fillctr, ssorted, dsorted);

  const int NB = (NND + 63) / 64;  // 782

  node_fused<<<NB, 128, 0, stream>>>(coordf,
      pa.wt[0], bq, gq, beq,
      pa.wt[1], bk, gk, bek,
      pa.wt[2], bm1, gm, bem, pa.wt[3], bm2,
      pa.wt[4], bb1, gb, beb, pa.wt[5], bb2,
      pa.wt[8], bc1, pa.wt[9],
      qt, kmb, (float*)d_out + (size_t)NND * DN);

  edge_kernel<<<NED / 64, 128, 0, stream>>>(qt, kmb, pa.wt[6], pa.wt[7],
                                            bw1, gw, bew, bw2, ssorted, dsorted,
                                            hacc, colsum16);

  prep_wn1<<<128, 256, 0, stream>>>(Wn1, colsum16, Wn1T);

  final_h<<<NB, 128, 0, stream>>>(node_feat, hacc, Wn1T, bn1,
                                  pa.wt[10], bn2, (float*)d_out);
}

// Round 11
// 677.931 us; speedup vs baseline: 1.0889x; 1.0889x over previous
//
#include <hip/hip_runtime.h>
#include <cstdint>
#include <cstddef>

#define DN 128
#define NND 50000
#define NED 512000
#define NSCAN 49   // ceil(NND/1024)

typedef __attribute__((ext_vector_type(8))) short bf8;
typedef __attribute__((ext_vector_type(4))) float f4;
typedef unsigned short us;

__device__ __forceinline__ us f2bf(float f){
  union { float f; unsigned int u; } c; c.f = f;
  unsigned int r = c.u + 0x7fffu + ((c.u >> 16) & 1u);
  return (us)(r >> 16);
}
__device__ __forceinline__ float bf2f(us u){
  union { unsigned int u; float f; } c; c.u = ((unsigned int)u) << 16;
  return c.f;
}
// mish(x) = x*tanh(softplus(x)) = x*(u^2-1)/(u^2+1), u = 1+exp(x)
__device__ __forceinline__ float mishf(float x){
  float e = __expf(x);
  float u = 1.f + e;
  float u2 = u * u;
  float t = __fdividef(u2 - 1.f, u2 + 1.f);
  return x * ((x > 20.f) ? 1.f : t);
}

#define MFMA16(a, b, c) __builtin_amdgcn_mfma_f32_16x16x32_bf16((a), (b), (c), 0, 0, 0)

// LDS fragment read: row-major [rows][K=128] bf16 with (row&7)<<4 byte XOR swizzle.
__device__ __forceinline__ bf8 lds_frag(const us* base, int row, int kElem){
  int byte = row * 256 + kElem * 2;
  byte ^= (row & 7) << 4;
  return *(const bf8*)((const char*)base + byte);
}
// Global weight fragment: W^T stored [Nout][K] bf16, plain row-major.
__device__ __forceinline__ bf8 gfrag(const us* W, int n, int K, int kElem){
  return *(const bf8*)(W + (size_t)n * K + kElem);
}

// ======== wave-local 32-row x 128-col primitives (zero cross-wave sync) ========
__device__ __forceinline__ void loadA32(const us* T, int g, int s, bf8 (&a)[2][4]){
#pragma unroll
  for (int rt = 0; rt < 2; ++rt)
#pragma unroll
    for (int kk = 0; kk < 4; ++kk)
      a[rt][kk] = lds_frag(T, rt*16 + s, kk*32 + g*8);
}

__device__ __forceinline__ void gemm32(const bf8 (&a)[2][4], const us* __restrict__ WT,
                                       int K, int kOff, const float* __restrict__ bias,
                                       bool init, int g, int s, f4 (&acc)[2][8]){
  if (init){
#pragma unroll
    for (int ct = 0; ct < 8; ++ct){
      float bv = bias ? bias[ct*16 + s] : 0.f;
      f4 t = {bv, bv, bv, bv};
      acc[0][ct] = t; acc[1][ct] = t;
    }
  }
#pragma unroll
  for (int ct = 0; ct < 8; ++ct){
    int n = ct*16 + s;
#pragma unroll
    for (int kk = 0; kk < 4; ++kk){
      bf8 b = gfrag(WT, n, K, kOff + kk*32 + g*8);
      acc[0][ct] = MFMA16(a[0][kk], b, acc[0][ct]);
      acc[1][ct] = MFMA16(a[1][kk], b, acc[1][ct]);
    }
  }
}

// LayerNorm over the 128-wide row fully in-wave + mish.
__device__ __forceinline__ void ln_mish32(f4 (&acc)[2][8],
                                          const float* __restrict__ gam,
                                          const float* __restrict__ bet, int s){
#pragma unroll
  for (int rt = 0; rt < 2; ++rt){
    float mu[4], rs[4];
#pragma unroll
    for (int reg = 0; reg < 4; ++reg){
      float sm = 0.f, sq = 0.f;
#pragma unroll
      for (int ct = 0; ct < 8; ++ct){ float v = acc[rt][ct][reg]; sm += v; sq += v*v; }
#pragma unroll
      for (int m = 1; m < 16; m <<= 1){ sm += __shfl_xor(sm, m, 64); sq += __shfl_xor(sq, m, 64); }
      float mm = sm * (1.f/128.f);
      float var = sq * (1.f/128.f) - mm*mm;
      mu[reg] = mm; rs[reg] = rsqrtf(var + 1e-5f);
    }
#pragma unroll
    for (int ct = 0; ct < 8; ++ct){
      float gv = gam[ct*16 + s], bv = bet[ct*16 + s];
#pragma unroll
      for (int reg = 0; reg < 4; ++reg)
        acc[rt][ct][reg] = mishf((acc[rt][ct][reg] - mu[reg]) * rs[reg] * gv + bv);
    }
  }
}

__device__ __forceinline__ void mish32(f4 (&acc)[2][8]){
#pragma unroll
  for (int rt = 0; rt < 2; ++rt)
#pragma unroll
    for (int ct = 0; ct < 8; ++ct)
#pragma unroll
      for (int reg = 0; reg < 4; ++reg)
        acc[rt][ct][reg] = mishf(acc[rt][ct][reg]);
}

__device__ __forceinline__ void writeT32(us* T, int g, int s, const f4 (&A)[2][8]){
#pragma unroll
  for (int rt = 0; rt < 2; ++rt)
#pragma unroll
    for (int ct = 0; ct < 8; ++ct)
#pragma unroll
      for (int reg = 0; reg < 4; ++reg){
        int row = rt*16 + g*4 + reg, col = ct*16 + s;
        int byte = row*256 + col*2; byte ^= (row & 7) << 4;
        *(us*)((char*)T + byte) = f2bf(A[rt][ct][reg]);
      }
}

template<int OUT_BF16>
__device__ __forceinline__ void store32(void* outp, int row0, int g, int s, int ostride,
                                        const f4 (&A)[2][8]){
#pragma unroll
  for (int rt = 0; rt < 2; ++rt)
#pragma unroll
    for (int ct = 0; ct < 8; ++ct)
#pragma unroll
      for (int reg = 0; reg < 4; ++reg){
        int row = row0 + rt*16 + g*4 + reg;
        if (row < NND){
          int col = ct*16 + s;
          if constexpr (OUT_BF16 != 0)
            ((us*)outp)[(size_t)row*ostride + col] = f2bf(A[rt][ct][reg]);
          else
            ((float*)outp)[(size_t)row*ostride + col] = A[rt][ct][reg];
        }
      }
}

// stage 16 rows (row-half hh) of a f32 [*,128] matrix into T as bf16, 4 lanes/row
__device__ __forceinline__ void stageF32(us* T, const float* __restrict__ src,
                                         int row0, int hh, int r, int c4, int ostride){
  int grow = row0 + hh*16 + r; if (grow >= NND) grow = NND - 1;
  const f4* sp = (const f4*)(src + (size_t)grow * ostride + c4 * 32);
  int lrow = hh*16 + r;
#pragma unroll
  for (int j = 0; j < 4; ++j){
    f4 v0 = sp[2*j], v1 = sp[2*j+1];
    bf8 o;
#pragma unroll
    for (int q = 0; q < 4; ++q){ o[q] = (short)f2bf(v0[q]); o[4+q] = (short)f2bf(v1[q]); }
    int byte = lrow*256 + c4*64 + j*16; byte ^= (lrow & 7) << 4;
    *(bf8*)((char*)T + byte) = o;
  }
}

// ---------- Fused node chains: 2-wave blocks, 32-row waves, barrier-free ----------
// (128,3): VGPR cap ~170 covers the kernel's natural ~156 (R10 evidence) — no
// spill (R3 lesson), occupancy 3 waves/SIMD vs R10's uncapped collapse.
__global__ __launch_bounds__(128, 3)
void node_fused(const float* __restrict__ X,
                const us* __restrict__ WqT,  const float* __restrict__ bq,
                const float* __restrict__ gq, const float* __restrict__ beq,
                const us* __restrict__ WkT,  const float* __restrict__ bk,
                const float* __restrict__ gk, const float* __restrict__ bek,
                const us* __restrict__ Wm1T, const float* __restrict__ bm1,
                const float* __restrict__ gm, const float* __restrict__ bem,
                const us* __restrict__ Wm2T, const float* __restrict__ bm2,
                const us* __restrict__ Wb1T, const float* __restrict__ bb1,
                const float* __restrict__ gb, const float* __restrict__ beb,
                const us* __restrict__ Wb2T, const float* __restrict__ bb2,
                const us* __restrict__ Wc1T, const float* __restrict__ bc1,
                const us* __restrict__ Wc2T,
                us* __restrict__ qt, us* __restrict__ kmb, float* __restrict__ xout)
{
  __shared__ us Tsh[2][32 * DN];   // 8KB per wave

  const int tid = threadIdx.x;
  const int lane = tid & 63, w = tid >> 6;
  const int g = lane >> 4, s = lane & 15;
  const int r = lane >> 2, c4 = lane & 3;
  const int row0 = blockIdx.x * 64 + w * 32;
  us* T = (us*)Tsh[w];

  stageF32(T, X, row0, 0, r, c4, DN);
  stageF32(T, X, row0, 1, r, c4, DN);

  bf8 a[2][4], a2[2][4];
  loadA32(T, g, s, a);       // X frags live across all 5 chains
  f4 acc[2][8];

  // ---- q ----
  gemm32(a, WqT, DN, 0, bq, true, g, s, acc);
  ln_mish32(acc, gq, beq, s);
  store32<1>((void*)qt, row0, g, s, DN, acc);

  // ---- k ----
  gemm32(a, WkT, DN, 0, bk, true, g, s, acc);
  ln_mish32(acc, gk, bek, s);
  store32<1>((void*)kmb, row0, g, s, 384, acc);

  // ---- m (2 GEMM) ----
  gemm32(a, Wm1T, DN, 0, bm1, true, g, s, acc);
  ln_mish32(acc, gm, bem, s);
  writeT32(T, g, s, acc);
  loadA32(T, g, s, a2);
  gemm32(a2, Wm2T, DN, 0, bm2, true, g, s, acc);
  store32<1>((void*)(kmb + 128), row0, g, s, 384, acc);

  // ---- b (2 GEMM) ----
  gemm32(a, Wb1T, DN, 0, bb1, true, g, s, acc);
  ln_mish32(acc, gb, beb, s);
  writeT32(T, g, s, acc);
  loadA32(T, g, s, a2);
  gemm32(a2, Wb2T, DN, 0, bb2, true, g, s, acc);
  store32<1>((void*)(kmb + 256), row0, g, s, 384, acc);

  // ---- c (2 GEMM, no LN) ----
  gemm32(a, Wc1T, DN, 0, bc1, true, g, s, acc);
  mish32(acc);
  writeT32(T, g, s, acc);
  loadA32(T, g, s, a2);
  gemm32(a2, Wc2T, DN, 0, nullptr, true, g, s, acc);
  store32<0>((void*)xout, row0, g, s, DN, acc);
}

// ---------- CSR build ----------
__global__ void csr_count(const int* __restrict__ dst, int* __restrict__ deg){
  int e = blockIdx.x * 256 + threadIdx.x;
  if (e < NED) atomicAdd(&deg[dst[e]], 1);
}

__global__ __launch_bounds__(1024) void csr_blocksum(const int* __restrict__ deg,
                                                     int* __restrict__ bsum){
  __shared__ int sb[1024];
  int t = threadIdx.x, idx = blockIdx.x * 1024 + t;
  sb[t] = (idx < NND) ? deg[idx] : 0;
  __syncthreads();
  for (int off = 512; off > 0; off >>= 1){
    if (t < off) sb[t] += sb[t + off];
    __syncthreads();
  }
  if (t == 0) bsum[blockIdx.x] = sb[0];
}

__global__ void csr_scanroot(const int* __restrict__ bsum, int* __restrict__ boff){
  if (threadIdx.x == 0){
    int run = 0;
    for (int b = 0; b < NSCAN; ++b){ boff[b] = run; run += bsum[b]; }
  }
}

__global__ __launch_bounds__(1024) void csr_scatter(const int* __restrict__ deg,
                                                    const int* __restrict__ boff,
                                                    int* __restrict__ fillctr){
  __shared__ int ss[1024];
  int t = threadIdx.x, idx = blockIdx.x * 1024 + t;
  int v = (idx < NND) ? deg[idx] : 0;
  ss[t] = v;
  __syncthreads();
  for (int off = 1; off < 1024; off <<= 1){
    int x = (t >= off) ? ss[t - off] : 0;
    __syncthreads();
    ss[t] += x;
    __syncthreads();
  }
  if (idx < NND){
    int p = boff[blockIdx.x] + ss[t] - v;
    fillctr[idx] = p;
  }
}

__global__ void csr_fill(const int* __restrict__ src, const int* __restrict__ dst,
                         int* __restrict__ fillctr,
                         int* __restrict__ ssorted, int* __restrict__ dsorted){
  int e = blockIdx.x * 256 + threadIdx.x;
  if (e < NED){
    int d = dst[e];
    int p = atomicAdd(&fillctr[d], 1);
    ssorted[p] = src[e];
    dsorted[p] = d;
  }
}

// ---------- Edge pass: 2-wave blocks, 32 sorted edges per wave, zero barriers,
// 2x B-reuse, wave-local segment-sum. (128,4): cap 128 >= proven 84 VGPR. ----------
__global__ __launch_bounds__(128, 4)
void edge_kernel(const us* __restrict__ qtab,
                 const us* __restrict__ kmb,   // [N][384]: k|m|b
                 const us* __restrict__ W1T,
                 const us* __restrict__ W2T,
                 const float* __restrict__ bw1,
                 const float* __restrict__ gwp,
                 const float* __restrict__ bewp,
                 const float* __restrict__ bw2,
                 const int* __restrict__ ssorted,
                 const int* __restrict__ dsorted,
                 float* __restrict__ hacc,      // [N][128] f32, atomic accumulate
                 float* __restrict__ colsum16)  // [16][128] f32 slices
{
  __shared__ us Tsh[2][32 * DN];   // per-wave tile: rel -> t -> p
  __shared__ int dsh[2][32];

  const int tid = threadIdx.x;
  const int lane = tid & 63, w = tid >> 6;
  const int g = lane >> 4, s = lane & 15;
  const int r = lane >> 2, c4 = lane & 3;

  // XCD-chunked swizzle (concurrent blocks cover a narrow sorted window)
  const int nchunk = gridDim.x >> 3;
  const int swz = (blockIdx.x & 7) * nchunk + (blockIdx.x >> 3);
  const int e0w = swz * 64 + w * 32;
  us* T = (us*)Tsh[w];
  int* dloc = dsh[w];

  // gather + rel for 32 edges, two 16-row halves (staging regs reused)
#pragma unroll
  for (int hh = 0; hh < 2; ++hh){
    int e = e0w + hh*16 + r;
    int sn = ssorted[e], dn = dsorted[e];
    const bf8* qp = (const bf8*)(qtab + (size_t)sn * DN + c4 * 32);
    const us*  kb = kmb + (size_t)dn * 384 + c4 * 32;
    bf8 qv[4], kv[4], mv[4], bv[4];
#pragma unroll
    for (int j = 0; j < 4; ++j){
      qv[j] = qp[j];
      kv[j] = *(const bf8*)(kb + j*8);
      mv[j] = *(const bf8*)(kb + 128 + j*8);
      bv[j] = *(const bf8*)(kb + 256 + j*8);
    }
    if (c4 == 0) dloc[hh*16 + r] = dn;

    float ss = 0.f;
#pragma unroll
    for (int j = 0; j < 4; ++j)
#pragma unroll
      for (int q = 0; q < 8; ++q){
        float d = bf2f((us)qv[j][q]) - bf2f((us)kv[j][q]);
        ss += d * d;
      }
    ss += __shfl_xor(ss, 1, 64);
    ss += __shfl_xor(ss, 2, 64);
    float rinv = rsqrtf(ss + 1e-8f);

    int lrow = hh*16 + r;
#pragma unroll
    for (int j = 0; j < 4; ++j){
      bf8 o;
#pragma unroll
      for (int q = 0; q < 8; ++q){
        float d = bf2f((us)qv[j][q]) - bf2f((us)kv[j][q]);
        float v = d * rinv * bf2f((us)mv[j][q]) + bf2f((us)bv[j][q]);
        o[q] = (short)f2bf(v);
      }
      int byte = lrow*256 + c4*64 + j*16; byte ^= (lrow & 7) << 4;
      *(bf8*)((char*)T + byte) = o;
    }
  }

  // GEMM1 -> in-wave LN+mish -> GEMM2 (acc reused) -> exp
  bf8 a[2][4];
  loadA32(T, g, s, a);
  f4 acc[2][8];
  gemm32(a, W1T, DN, 0, bw1, true, g, s, acc);
  ln_mish32(acc, gwp, bewp, s);
  writeT32(T, g, s, acc);
  bf8 a2[2][4];
  loadA32(T, g, s, a2);
  gemm32(a2, W2T, DN, 0, bw2, true, g, s, acc);
#pragma unroll
  for (int rt = 0; rt < 2; ++rt)
#pragma unroll
    for (int ct = 0; ct < 8; ++ct)
#pragma unroll
      for (int reg = 0; reg < 4; ++reg)
        acc[rt][ct][reg] = __expf(acc[rt][ct][reg]);

  // p -> wave tile (in-wave LDS ordering; no barrier needed)
  writeT32(T, g, s, acc);

  { // wave-local segment-sum: lane owns cols (2*lane, 2*lane+1), walks 32 sorted rows
    int cA = lane * 2;
    float run0 = 0.f, run1 = 0.f, cs0 = 0.f, cs1 = 0.f;
    int prev = dloc[0];
#pragma unroll 8
    for (int r2 = 0; r2 < 32; ++r2){
      int byte = r2*256 + cA*2; byte ^= (r2 & 7) << 4;
      unsigned int v = *(const unsigned int*)((const char*)T + byte);
      float f0 = bf2f((us)(v & 0xffffu));
      float f1 = bf2f((us)(v >> 16));
      int d = dloc[r2];
      cs0 += f0; cs1 += f1;
      if (d != prev){
        atomicAdd(&hacc[(size_t)prev * DN + cA], run0);
        atomicAdd(&hacc[(size_t)prev * DN + cA + 1], run1);
        run0 = f0; run1 = f1; prev = d;
      } else {
        run0 += f0; run1 += f1;
      }
    }
    atomicAdd(&hacc[(size_t)prev * DN + cA], run0);
    atomicAdd(&hacc[(size_t)prev * DN + cA + 1], run1);
    int slice = ((blockIdx.x & 7) << 1) | w;
    atomicAdd(&colsum16[slice * DN + cA], cs0);
    atomicAdd(&colsum16[slice * DN + cA + 1], cs1);
  }
}

// ---------- prep Wn1^T with 1/colsum absorbed into rows 128..255 ----------
__global__ __launch_bounds__(256)
void prep_wn1(const float* __restrict__ Wn1, const float* __restrict__ colsum16,
              us* __restrict__ wt){
  __shared__ float rcsh[DN];
  int tid = threadIdx.x;
  if (tid < DN){
    float ssum = 0.f;
#pragma unroll
    for (int x = 0; x < 16; ++x) ssum += colsum16[x * DN + tid];
    rcsh[tid] = 1.f / ssum;
  }
  __syncthreads();
  int idx = blockIdx.x * 256 + tid;     // 128 blocks x 256 = 32768 = 128n x 256k
  int n = idx >> 8, k = idx & 255;
  float v = Wn1[(size_t)k * DN + n];
  if (k >= 128) v *= rcsh[k - 128];
  wt[idx] = f2bf(v);
}

// ---------- final: h = mish(concat[node_feat, hacc] @ Wn1'(rcs-absorbed) + bn1) @ Wn2 + bn2 ----------
__global__ __launch_bounds__(128, 3)
void final_h(const float* __restrict__ nodef,
             const float* __restrict__ hacc,
             const us* __restrict__ Wn1T,    // [n][256], rows 128.. pre-scaled by rcs
             const float* __restrict__ bn1,
             const us* __restrict__ Wn2T,
             const float* __restrict__ bn2,
             float* __restrict__ outh)
{
  __shared__ us Tsh[2][32 * DN];

  const int tid = threadIdx.x;
  const int lane = tid & 63, w = tid >> 6;
  const int g = lane >> 4, s = lane & 15;
  const int r = lane >> 2, c4 = lane & 3;
  const int row0 = blockIdx.x * 64 + w * 32;
  us* T = (us*)Tsh[w];

  bf8 a[2][4];
  f4 acc[2][8];

  // K-half 0: node_feat
  stageF32(T, nodef, row0, 0, r, c4, DN);
  stageF32(T, nodef, row0, 1, r, c4, DN);
  loadA32(T, g, s, a);
  gemm32(a, Wn1T, 256, 0, bn1, true, g, s, acc);

  // K-half 1: hacc (raw; rcs absorbed into Wn1T)
  stageF32(T, hacc, row0, 0, r, c4, DN);
  stageF32(T, hacc, row0, 1, r, c4, DN);
  loadA32(T, g, s, a);
  gemm32(a, Wn1T, 256, 128, nullptr, false, g, s, acc);

  mish32(acc);
  writeT32(T, g, s, acc);
  loadA32(T, g, s, a);
  gemm32(a, Wn2T, DN, 0, bn2, true, g, s, acc);
  store32<0>((void*)outh, row0, g, s, DN, acc);
}

struct WPrepArgs {
  const float* w[12];
  us* wt[12];
};

// W^T bf16 (K=128): wt[n*128 + k] = bf16(W[k*128 + n])
__global__ void prep_weights(WPrepArgs a){
  int widx = blockIdx.y;
  int idx = blockIdx.x * 256 + threadIdx.x;   // 64 blocks x 256 = 16384
  int n = idx >> 7;
  int k = idx & 127;
  a.wt[widx][idx] = f2bf(a.w[widx][(size_t)k * DN + n]);
}

extern "C" void kernel_launch(void* const* d_in, const int* in_sizes, int n_in,
                              void* d_out, int out_size, void* d_ws, size_t ws_size,
                              hipStream_t stream) {
  const float* node_feat = (const float*)d_in[0];
  const float* coordf    = (const float*)d_in[1];
  const float* Wq  = (const float*)d_in[2];
  const float* bq  = (const float*)d_in[3];
  const float* gq  = (const float*)d_in[4];
  const float* beq = (const float*)d_in[5];
  const float* Wk  = (const float*)d_in[6];
  const float* bk  = (const float*)d_in[7];
  const float* gk  = (const float*)d_in[8];
  const float* bek = (const float*)d_in[9];
  const float* Wm1 = (const float*)d_in[10];
  const float* bm1 = (const float*)d_in[11];
  const float* gm  = (const float*)d_in[12];
  const float* bem = (const float*)d_in[13];
  const float* Wm2 = (const float*)d_in[14];
  const float* bm2 = (const float*)d_in[15];
  const float* Wb1 = (const float*)d_in[16];
  const float* bb1 = (const float*)d_in[17];
  const float* gb  = (const float*)d_in[18];
  const float* beb = (const float*)d_in[19];
  const float* Wb2 = (const float*)d_in[20];
  const float* bb2 = (const float*)d_in[21];
  const float* Ww1 = (const float*)d_in[22];
  const float* bw1 = (const float*)d_in[23];
  const float* gw  = (const float*)d_in[24];
  const float* bew = (const float*)d_in[25];
  const float* Ww2 = (const float*)d_in[26];
  const float* bw2 = (const float*)d_in[27];
  const float* Wn1 = (const float*)d_in[28];
  const float* bn1 = (const float*)d_in[29];
  const float* Wn2 = (const float*)d_in[30];
  const float* bn2 = (const float*)d_in[31];
  const float* Wc1 = (const float*)d_in[32];
  const float* bc1 = (const float*)d_in[33];
  const float* Wc2 = (const float*)d_in[34];
  const int* srcI  = (const int*)d_in[35];
  const int* dstI  = (const int*)d_in[36];

  char* ws = (char*)d_ws;
  size_t off = 0;
  auto alloc = [&](size_t bytes) -> char* {
    char* p = ws + off;
    off += (bytes + 255) & ~(size_t)255;
    return p;
  };
  us*    qt       = (us*)alloc((size_t)NND * DN * 2);
  us*    kmb      = (us*)alloc((size_t)NND * 384 * 2);
  float* hacc     = (float*)alloc((size_t)NND * DN * 4);
  float* colsum16 = (float*)alloc(16 * DN * 4);
  int*   deg      = (int*)alloc((size_t)NND * 4);
  int*   fillctr  = (int*)alloc((size_t)NND * 4);
  int*   ssorted  = (int*)alloc((size_t)NED * 4);
  int*   dsorted  = (int*)alloc((size_t)NED * 4);
  int*   bsum     = (int*)alloc((size_t)NSCAN * 4);
  int*   boff     = (int*)alloc((size_t)NSCAN * 4);
  us*    wtb      = (us*)alloc((size_t)13 * 16384 * 2);   // 11 K=128 + 1 K=256 (2 slots)

  // zero the atomic accumulators (hacc + colsum16 are adjacent)
  hipMemsetAsync(hacc, 0, (size_t)NND * DN * 4 + 16 * DN * 4, stream);
  hipMemsetAsync(deg, 0, (size_t)NND * 4, stream);

  WPrepArgs pa;
  const float* wsrc[11] = {Wq, Wk, Wm1, Wm2, Wb1, Wb2, Ww1, Ww2, Wc1, Wc2, Wn2};
  for (int i = 0; i < 11; ++i){
    pa.w[i] = wsrc[i];
    pa.wt[i] = wtb + (size_t)i * 16384;
  }
  us* Wn1T = wtb + (size_t)11 * 16384;   // occupies slots 11+12 (32768 us)
  prep_weights<<<dim3(64, 11), 256, 0, stream>>>(pa);

  // CSR positions + edge sort by dst
  csr_count<<<(NED + 255) / 256, 256, 0, stream>>>(dstI, deg);
  csr_blocksum<<<NSCAN, 1024, 0, stream>>>(deg, bsum);
  csr_scanroot<<<1, 64, 0, stream>>>(bsum, boff);
  csr_scatter<<<NSCAN, 1024, 0, stream>>>(deg, boff, fillctr);
  csr_fill<<<(NED + 255) / 256, 256, 0, stream>>>(srcI, dstI, fillctr, ssorted, dsorted);

  const int NB = (NND + 63) / 64;  // 782

  node_fused<<<NB, 128, 0, stream>>>(coordf,
      pa.wt[0], bq, gq, beq,
      pa.wt[1], bk, gk, bek,
      pa.wt[2], bm1, gm, bem, pa.wt[3], bm2,
      pa.wt[4], bb1, gb, beb, pa.wt[5], bb2,
      pa.wt[8], bc1, pa.wt[9],
      qt, kmb, (float*)d_out + (size_t)NND * DN);

  edge_kernel<<<NED / 64, 128, 0, stream>>>(qt, kmb, pa.wt[6], pa.wt[7],
                                            bw1, gw, bew, bw2, ssorted, dsorted,
                                            hacc, colsum16);

  prep_wn1<<<128, 256, 0, stream>>>(Wn1, colsum16, Wn1T);

  final_h<<<NB, 128, 0, stream>>>(node_feat, hacc, Wn1T, bn1,
                                  pa.wt[10], bn2, (float*)d_out);
}

// Round 12
// 522.102 us; speedup vs baseline: 1.4140x; 1.2985x over previous
//
#include <hip/hip_runtime.h>
#include <cstdint>
#include <cstddef>

#define DN 128
#define NND 50000
#define NED 512000
#define NSCAN 49   // ceil(NND/1024)

typedef __attribute__((ext_vector_type(8))) short bf8;
typedef __attribute__((ext_vector_type(4))) float f4;
typedef unsigned short us;

__device__ __forceinline__ us f2bf(float f){
  union { float f; unsigned int u; } c; c.f = f;
  unsigned int r = c.u + 0x7fffu + ((c.u >> 16) & 1u);
  return (us)(r >> 16);
}
__device__ __forceinline__ float bf2f(us u){
  union { unsigned int u; float f; } c; c.u = ((unsigned int)u) << 16;
  return c.f;
}
// mish(x) = x*tanh(softplus(x)) = x*(u^2-1)/(u^2+1), u = 1+exp(x)
__device__ __forceinline__ float mishf(float x){
  float e = __expf(x);
  float u = 1.f + e;
  float u2 = u * u;
  float t = __fdividef(u2 - 1.f, u2 + 1.f);
  return x * ((x > 20.f) ? 1.f : t);
}

#define MFMA16(a, b, c) __builtin_amdgcn_mfma_f32_16x16x32_bf16((a), (b), (c), 0, 0, 0)

// LDS fragment read: row-major [rows][K] bf16 with (row&7)<<4 byte XOR swizzle.
__device__ __forceinline__ bf8 lds_frag(const us* base, int row, int rowStrideB, int kElem){
  int byte = row * rowStrideB + kElem * 2;
  byte ^= (row & 7) << 4;
  return *(const bf8*)((const char*)base + byte);
}
// Global weight fragment: W^T stored [Nout][K] bf16, plain row-major.
__device__ __forceinline__ bf8 gfrag(const us* W, int n, int K, int kElem){
  return *(const bf8*)(W + (size_t)n * K + kElem);
}

template<int OUT_BF16>
__device__ __forceinline__ void store_tile(void* outp, int nrows, int r0,
                                           int wr, int wc, int g, int s, int ostride,
                                           const f4 (&A)[2][4]){
#pragma unroll
  for (int rt = 0; rt < 2; ++rt)
#pragma unroll
    for (int ct = 0; ct < 4; ++ct)
#pragma unroll
      for (int reg = 0; reg < 4; ++reg){
        int row = r0 + wr*32 + rt*16 + g*4 + reg;
        if (row < nrows){
          int col = wc*64 + ct*16 + s;
          float v = A[rt][ct][reg];
          if constexpr (OUT_BF16 != 0)
            ((us*)outp)[(size_t)row*ostride + col] = f2bf(v);
          else
            ((float*)outp)[(size_t)row*ostride + col] = v;
        }
      }
}

// GEMM: acc = bias + A(regs) @ W^T  (2 row-frags x 4 col-frags; 2x B reuse)
__device__ __forceinline__ void gemm_reg(const bf8 (&a)[2][4], const us* __restrict__ WT,
                                         const float* __restrict__ bias,
                                         int wc, int g, int s, f4 (&acc)[2][4]){
#pragma unroll
  for (int ct = 0; ct < 4; ++ct){
    float bv = bias ? bias[wc*64 + ct*16 + s] : 0.f;
    f4 t = {bv, bv, bv, bv};
    acc[0][ct] = t; acc[1][ct] = t;
  }
#pragma unroll
  for (int ct = 0; ct < 4; ++ct){
    int n = wc*64 + ct*16 + s;
#pragma unroll
    for (int kk = 0; kk < 4; ++kk){
      bf8 b = gfrag(WT, n, DN, kk*32 + g*8);
      acc[0][ct] = MFMA16(a[0][kk], b, acc[0][ct]);
      acc[1][ct] = MFMA16(a[1][kk], b, acc[1][ct]);
    }
  }
}

// LN across the 128-wide row (two waves share a row) + mish. Uses buf parity to
// avoid WAR races on the stats arrays between consecutive chains.
__device__ __forceinline__ void ln_mish(f4 (&acc)[2][4],
                                        const float* __restrict__ gam,
                                        const float* __restrict__ bet,
                                        int wr, int wc, int g, int s,
                                        float (*rowsum)[64][2], float (*rowsq)[64][2],
                                        int buf){
  float gv[4], bev[4];
#pragma unroll
  for (int ct = 0; ct < 4; ++ct){ int n = wc*64 + ct*16 + s; gv[ct] = gam[n]; bev[ct] = bet[n]; }
#pragma unroll
  for (int rt = 0; rt < 2; ++rt)
#pragma unroll
    for (int reg = 0; reg < 4; ++reg){
      float sm = acc[rt][0][reg] + acc[rt][1][reg] + acc[rt][2][reg] + acc[rt][3][reg];
      float sq = acc[rt][0][reg]*acc[rt][0][reg] + acc[rt][1][reg]*acc[rt][1][reg]
               + acc[rt][2][reg]*acc[rt][2][reg] + acc[rt][3][reg]*acc[rt][3][reg];
#pragma unroll
      for (int m = 1; m < 16; m <<= 1){ sm += __shfl_xor(sm, m, 64); sq += __shfl_xor(sq, m, 64); }
      if (s == 0){
        int row = wr*32 + rt*16 + g*4 + reg;
        rowsum[buf][row][wc] = sm; rowsq[buf][row][wc] = sq;
      }
    }
  __syncthreads();
#pragma unroll
  for (int rt = 0; rt < 2; ++rt)
#pragma unroll
    for (int reg = 0; reg < 4; ++reg){
      int row = wr*32 + rt*16 + g*4 + reg;
      float sm = rowsum[buf][row][0] + rowsum[buf][row][1];
      float sq = rowsq[buf][row][0] + rowsq[buf][row][1];
      float mu = sm * (1.f/128.f);
      float var = sq * (1.f/128.f) - mu*mu;
      float rs = rsqrtf(var + 1e-5f);
#pragma unroll
      for (int ct = 0; ct < 4; ++ct)
        acc[rt][ct][reg] = mishf((acc[rt][ct][reg] - mu) * rs * gv[ct] + bev[ct]);
    }
}

__device__ __forceinline__ void write_T(us* Tsh, int wr, int wc, int g, int s,
                                        const f4 (&A)[2][4]){
#pragma unroll
  for (int rt = 0; rt < 2; ++rt)
#pragma unroll
    for (int ct = 0; ct < 4; ++ct)
#pragma unroll
      for (int reg = 0; reg < 4; ++reg){
        int row = wr*32 + rt*16 + g*4 + reg;
        int col = wc*64 + ct*16 + s;
        int byte = row*256 + col*2; byte ^= (row & 7) << 4;
        *(us*)((char*)Tsh + byte) = f2bf(A[rt][ct][reg]);
      }
}

__device__ __forceinline__ void load_a2(const us* Tsh, int wr, int g, int s, bf8 (&a2)[2][4]){
#pragma unroll
  for (int rt = 0; rt < 2; ++rt)
#pragma unroll
    for (int kk = 0; kk < 4; ++kk)
      a2[rt][kk] = lds_frag(Tsh, wr*32 + rt*16 + s, 256, kk*32 + g*8);
}

// ---- wave-local 32-row x 128-col primitives (edge kernel; zero cross-wave sync) ----
__device__ __forceinline__ void loadA32(const us* T, int g, int s, bf8 (&a)[2][4]){
#pragma unroll
  for (int rt = 0; rt < 2; ++rt)
#pragma unroll
    for (int kk = 0; kk < 4; ++kk)
      a[rt][kk] = lds_frag(T, rt*16 + s, 256, kk*32 + g*8);
}

__device__ __forceinline__ void gemm32(const bf8 (&a)[2][4], const us* __restrict__ WT,
                                       const float* __restrict__ bias,
                                       int g, int s, f4 (&acc)[2][8]){
#pragma unroll
  for (int ct = 0; ct < 8; ++ct){
    float bv = bias ? bias[ct*16 + s] : 0.f;
    f4 t = {bv, bv, bv, bv};
    acc[0][ct] = t; acc[1][ct] = t;
  }
#pragma unroll
  for (int ct = 0; ct < 8; ++ct){
    int n = ct*16 + s;
#pragma unroll
    for (int kk = 0; kk < 4; ++kk){
      bf8 b = gfrag(WT, n, DN, kk*32 + g*8);
      acc[0][ct] = MFMA16(a[0][kk], b, acc[0][ct]);
      acc[1][ct] = MFMA16(a[1][kk], b, acc[1][ct]);
    }
  }
}

// LayerNorm over the 128-wide row fully in-wave + mish.
__device__ __forceinline__ void ln_mish32(f4 (&acc)[2][8],
                                          const float* __restrict__ gam,
                                          const float* __restrict__ bet, int s){
#pragma unroll
  for (int rt = 0; rt < 2; ++rt){
    float mu[4], rs[4];
#pragma unroll
    for (int reg = 0; reg < 4; ++reg){
      float sm = 0.f, sq = 0.f;
#pragma unroll
      for (int ct = 0; ct < 8; ++ct){ float v = acc[rt][ct][reg]; sm += v; sq += v*v; }
#pragma unroll
      for (int m = 1; m < 16; m <<= 1){ sm += __shfl_xor(sm, m, 64); sq += __shfl_xor(sq, m, 64); }
      float mm = sm * (1.f/128.f);
      float var = sq * (1.f/128.f) - mm*mm;
      mu[reg] = mm; rs[reg] = rsqrtf(var + 1e-5f);
    }
#pragma unroll
    for (int ct = 0; ct < 8; ++ct){
      float gv = gam[ct*16 + s], bv = bet[ct*16 + s];
#pragma unroll
      for (int reg = 0; reg < 4; ++reg)
        acc[rt][ct][reg] = mishf((acc[rt][ct][reg] - mu[reg]) * rs[reg] * gv + bv);
    }
  }
}

__device__ __forceinline__ void writeT32(us* T, int g, int s, const f4 (&A)[2][8]){
#pragma unroll
  for (int rt = 0; rt < 2; ++rt)
#pragma unroll
    for (int ct = 0; ct < 8; ++ct)
#pragma unroll
      for (int reg = 0; reg < 4; ++reg){
        int row = rt*16 + g*4 + reg, col = ct*16 + s;
        int byte = row*256 + col*2; byte ^= (row & 7) << 4;
        *(us*)((char*)T + byte) = f2bf(A[rt][ct][reg]);
      }
}

// ---------- Fused node chains (R5 structure: 64-row block, 2x2 waves, 2x B reuse) ----------
__global__ __launch_bounds__(256, 2)
void node_fused(const float* __restrict__ X,
                const us* __restrict__ WqT,  const float* __restrict__ bq,
                const float* __restrict__ gq, const float* __restrict__ beq,
                const us* __restrict__ WkT,  const float* __restrict__ bk,
                const float* __restrict__ gk, const float* __restrict__ bek,
                const us* __restrict__ Wm1T, const float* __restrict__ bm1,
                const float* __restrict__ gm, const float* __restrict__ bem,
                const us* __restrict__ Wm2T, const float* __restrict__ bm2,
                const us* __restrict__ Wb1T, const float* __restrict__ bb1,
                const float* __restrict__ gb, const float* __restrict__ beb,
                const us* __restrict__ Wb2T, const float* __restrict__ bb2,
                const us* __restrict__ Wc1T, const float* __restrict__ bc1,
                const us* __restrict__ Wc2T,
                us* __restrict__ qt, us* __restrict__ kmb, float* __restrict__ xout)
{
  __shared__ us Ash[64 * DN];
  __shared__ float rowsum[2][64][2];
  __shared__ float rowsq[2][64][2];

  const int tid = threadIdx.x;
  const int r0 = blockIdx.x * 64;

  { // stage X rows -> bf16 swizzled LDS (once, shared by 8 GEMMs)
    int r = tid >> 2, c4 = tid & 3;
    int grow = r0 + r; if (grow >= NND) grow = NND - 1;
    const f4* sp = (const f4*)(X + (size_t)grow * DN + c4 * 32);
#pragma unroll
    for (int j = 0; j < 4; ++j){
      f4 v0 = sp[2*j], v1 = sp[2*j+1];
      bf8 o;
#pragma unroll
      for (int q = 0; q < 4; ++q){ o[q] = (short)f2bf(v0[q]); o[4+q] = (short)f2bf(v1[q]); }
      int byte = r*256 + c4*64 + j*16; byte ^= (r & 7) << 4;
      *(bf8*)((char*)Ash + byte) = o;
    }
  }
  __syncthreads();

  const int lane = tid & 63, w = tid >> 6;
  const int wr = w >> 1, wc = w & 1;
  const int g = lane >> 4, s = lane & 15;

  bf8 a[2][4];
#pragma unroll
  for (int rt = 0; rt < 2; ++rt)
#pragma unroll
    for (int kk = 0; kk < 4; ++kk)
      a[rt][kk] = lds_frag(Ash, wr*32 + rt*16 + s, 256, kk*32 + g*8);
  __syncthreads();   // all A-frag reads done -> Ash reusable as T

  f4 acc[2][4], acc2[2][4];
  bf8 a2[2][4];

  // ---- q ----
  gemm_reg(a, WqT, bq, wc, g, s, acc);
  ln_mish(acc, gq, beq, wr, wc, g, s, rowsum, rowsq, 0);
  store_tile<1>((void*)qt, NND, r0, wr, wc, g, s, DN, acc);

  // ---- k ----
  gemm_reg(a, WkT, bk, wc, g, s, acc);
  ln_mish(acc, gk, bek, wr, wc, g, s, rowsum, rowsq, 1);
  store_tile<1>((void*)kmb, NND, r0, wr, wc, g, s, 384, acc);

  // ---- m (2 GEMM) ----
  gemm_reg(a, Wm1T, bm1, wc, g, s, acc);
  ln_mish(acc, gm, bem, wr, wc, g, s, rowsum, rowsq, 0);
  write_T(Ash, wr, wc, g, s, acc);
  __syncthreads();
  load_a2(Ash, wr, g, s, a2);
#pragma unroll
  for (int ct = 0; ct < 4; ++ct){
    float bv = bm2[wc*64 + ct*16 + s]; f4 t = {bv,bv,bv,bv}; acc2[0][ct] = t; acc2[1][ct] = t;
  }
#pragma unroll
  for (int ct = 0; ct < 4; ++ct){
    int n = wc*64 + ct*16 + s;
#pragma unroll
    for (int kk = 0; kk < 4; ++kk){
      bf8 b = gfrag(Wm2T, n, DN, kk*32 + g*8);
      acc2[0][ct] = MFMA16(a2[0][kk], b, acc2[0][ct]);
      acc2[1][ct] = MFMA16(a2[1][kk], b, acc2[1][ct]);
    }
  }
  store_tile<1>((void*)(kmb + 128), NND, r0, wr, wc, g, s, 384, acc2);

  // ---- b (2 GEMM) ----
  gemm_reg(a, Wb1T, bb1, wc, g, s, acc);
  ln_mish(acc, gb, beb, wr, wc, g, s, rowsum, rowsq, 1);
  write_T(Ash, wr, wc, g, s, acc);
  __syncthreads();
  load_a2(Ash, wr, g, s, a2);
#pragma unroll
  for (int ct = 0; ct < 4; ++ct){
    float bv = bb2[wc*64 + ct*16 + s]; f4 t = {bv,bv,bv,bv}; acc2[0][ct] = t; acc2[1][ct] = t;
  }
#pragma unroll
  for (int ct = 0; ct < 4; ++ct){
    int n = wc*64 + ct*16 + s;
#pragma unroll
    for (int kk = 0; kk < 4; ++kk){
      bf8 b = gfrag(Wb2T, n, DN, kk*32 + g*8);
      acc2[0][ct] = MFMA16(a2[0][kk], b, acc2[0][ct]);
      acc2[1][ct] = MFMA16(a2[1][kk], b, acc2[1][ct]);
    }
  }
  store_tile<1>((void*)(kmb + 256), NND, r0, wr, wc, g, s, 384, acc2);

  // ---- c (2 GEMM, no LN) ----
  gemm_reg(a, Wc1T, bc1, wc, g, s, acc);
#pragma unroll
  for (int rt = 0; rt < 2; ++rt)
#pragma unroll
    for (int ct = 0; ct < 4; ++ct)
#pragma unroll
      for (int reg = 0; reg < 4; ++reg)
        acc[rt][ct][reg] = mishf(acc[rt][ct][reg]);
  __syncthreads();
  write_T(Ash, wr, wc, g, s, acc);
  __syncthreads();
  load_a2(Ash, wr, g, s, a2);
#pragma unroll
  for (int ct = 0; ct < 4; ++ct){ f4 t = {0,0,0,0}; acc2[0][ct] = t; acc2[1][ct] = t; }
#pragma unroll
  for (int ct = 0; ct < 4; ++ct){
    int n = wc*64 + ct*16 + s;
#pragma unroll
    for (int kk = 0; kk < 4; ++kk){
      bf8 b = gfrag(Wc2T, n, DN, kk*32 + g*8);
      acc2[0][ct] = MFMA16(a2[0][kk], b, acc2[0][ct]);
      acc2[1][ct] = MFMA16(a2[1][kk], b, acc2[1][ct]);
    }
  }
  store_tile<0>((void*)xout, NND, r0, wr, wc, g, s, DN, acc2);
}

// ---------- CSR build ----------
__global__ void csr_count(const int* __restrict__ dst, int* __restrict__ deg){
  int e = blockIdx.x * 256 + threadIdx.x;
  if (e < NED) atomicAdd(&deg[dst[e]], 1);
}

__global__ __launch_bounds__(1024) void csr_blocksum(const int* __restrict__ deg,
                                                     int* __restrict__ bsum){
  __shared__ int sb[1024];
  int t = threadIdx.x, idx = blockIdx.x * 1024 + t;
  sb[t] = (idx < NND) ? deg[idx] : 0;
  __syncthreads();
  for (int off = 512; off > 0; off >>= 1){
    if (t < off) sb[t] += sb[t + off];
    __syncthreads();
  }
  if (t == 0) bsum[blockIdx.x] = sb[0];
}

__global__ void csr_scanroot(const int* __restrict__ bsum, int* __restrict__ boff){
  if (threadIdx.x == 0){
    int run = 0;
    for (int b = 0; b < NSCAN; ++b){ boff[b] = run; run += bsum[b]; }
  }
}

__global__ __launch_bounds__(1024) void csr_scatter(const int* __restrict__ deg,
                                                    const int* __restrict__ boff,
                                                    int* __restrict__ fillctr){
  __shared__ int ss[1024];
  int t = threadIdx.x, idx = blockIdx.x * 1024 + t;
  int v = (idx < NND) ? deg[idx] : 0;
  ss[t] = v;
  __syncthreads();
  for (int off = 1; off < 1024; off <<= 1){
    int x = (t >= off) ? ss[t - off] : 0;
    __syncthreads();
    ss[t] += x;
    __syncthreads();
  }
  if (idx < NND){
    int p = boff[blockIdx.x] + ss[t] - v;
    fillctr[idx] = p;
  }
}

__global__ void csr_fill(const int* __restrict__ src, const int* __restrict__ dst,
                         int* __restrict__ fillctr,
                         int* __restrict__ ssorted, int* __restrict__ dsorted){
  int e = blockIdx.x * 256 + threadIdx.x;
  if (e < NED){
    int d = dst[e];
    int p = atomicAdd(&fillctr[d], 1);
    ssorted[p] = src[e];
    dsorted[p] = d;
  }
}

// ---------- Edge pass (R9 config, proven 274us): 256-thread blocks, 4 waves x
// 32 sorted edges, zero barriers, 2x B-reuse, wave-local segment-sum. ----------
__global__ __launch_bounds__(256, 2)
void edge_kernel(const us* __restrict__ qtab,
                 const us* __restrict__ kmb,   // [N][384]: k|m|b
                 const us* __restrict__ W1T,
                 const us* __restrict__ W2T,
                 const float* __restrict__ bw1,
                 const float* __restrict__ gwp,
                 const float* __restrict__ bewp,
                 const float* __restrict__ bw2,
                 const int* __restrict__ ssorted,
                 const int* __restrict__ dsorted,
                 float* __restrict__ hacc,      // [N][128] f32, atomic accumulate
                 float* __restrict__ colsum16)  // [16][128] f32 slices
{
  __shared__ us Tsh[4][32 * DN];   // per-wave tile: rel -> t -> p
  __shared__ int dsh[4][32];

  const int tid = threadIdx.x;
  const int lane = tid & 63, w = tid >> 6;
  const int g = lane >> 4, s = lane & 15;
  const int r = lane >> 2, c4 = lane & 3;

  // XCD-chunked swizzle (concurrent blocks cover a narrow sorted window)
  const int nchunk = gridDim.x >> 3;
  const int swz = (blockIdx.x & 7) * nchunk + (blockIdx.x >> 3);
  const int e0w = swz * 128 + w * 32;
  us* T = (us*)Tsh[w];
  int* dloc = dsh[w];

  // gather + rel for 32 edges, two 16-row halves (staging regs reused)
#pragma unroll
  for (int hh = 0; hh < 2; ++hh){
    int e = e0w + hh*16 + r;
    int sn = ssorted[e], dn = dsorted[e];
    const bf8* qp = (const bf8*)(qtab + (size_t)sn * DN + c4 * 32);
    const us*  kb = kmb + (size_t)dn * 384 + c4 * 32;
    bf8 qv[4], kv[4], mv[4], bv[4];
#pragma unroll
    for (int j = 0; j < 4; ++j){
      qv[j] = qp[j];
      kv[j] = *(const bf8*)(kb + j*8);
      mv[j] = *(const bf8*)(kb + 128 + j*8);
      bv[j] = *(const bf8*)(kb + 256 + j*8);
    }
    if (c4 == 0) dloc[hh*16 + r] = dn;

    float ss = 0.f;
#pragma unroll
    for (int j = 0; j < 4; ++j)
#pragma unroll
      for (int q = 0; q < 8; ++q){
        float d = bf2f((us)qv[j][q]) - bf2f((us)kv[j][q]);
        ss += d * d;
      }
    ss += __shfl_xor(ss, 1, 64);
    ss += __shfl_xor(ss, 2, 64);
    float rinv = rsqrtf(ss + 1e-8f);

    int lrow = hh*16 + r;
#pragma unroll
    for (int j = 0; j < 4; ++j){
      bf8 o;
#pragma unroll
      for (int q = 0; q < 8; ++q){
        float d = bf2f((us)qv[j][q]) - bf2f((us)kv[j][q]);
        float v = d * rinv * bf2f((us)mv[j][q]) + bf2f((us)bv[j][q]);
        o[q] = (short)f2bf(v);
      }
      int byte = lrow*256 + c4*64 + j*16; byte ^= (lrow & 7) << 4;
      *(bf8*)((char*)T + byte) = o;
    }
  }

  // GEMM1 -> in-wave LN+mish -> GEMM2 (acc reused) -> exp
  bf8 a[2][4];
  loadA32(T, g, s, a);
  f4 acc[2][8];
  gemm32(a, W1T, bw1, g, s, acc);
  ln_mish32(acc, gwp, bewp, s);
  writeT32(T, g, s, acc);
  bf8 a2[2][4];
  loadA32(T, g, s, a2);
  gemm32(a2, W2T, bw2, g, s, acc);
#pragma unroll
  for (int rt = 0; rt < 2; ++rt)
#pragma unroll
    for (int ct = 0; ct < 8; ++ct)
#pragma unroll
      for (int reg = 0; reg < 4; ++reg)
        acc[rt][ct][reg] = __expf(acc[rt][ct][reg]);

  // p -> wave tile (in-wave LDS ordering; no barrier needed)
  writeT32(T, g, s, acc);

  { // wave-local segment-sum: lane owns cols (2*lane, 2*lane+1), walks 32 sorted rows
    int cA = lane * 2;
    float run0 = 0.f, run1 = 0.f, cs0 = 0.f, cs1 = 0.f;
    int prev = dloc[0];
#pragma unroll 8
    for (int r2 = 0; r2 < 32; ++r2){
      int byte = r2*256 + cA*2; byte ^= (r2 & 7) << 4;
      unsigned int v = *(const unsigned int*)((const char*)T + byte);
      float f0 = bf2f((us)(v & 0xffffu));
      float f1 = bf2f((us)(v >> 16));
      int d = dloc[r2];
      cs0 += f0; cs1 += f1;
      if (d != prev){
        atomicAdd(&hacc[(size_t)prev * DN + cA], run0);
        atomicAdd(&hacc[(size_t)prev * DN + cA + 1], run1);
        run0 = f0; run1 = f1; prev = d;
      } else {
        run0 += f0; run1 += f1;
      }
    }
    atomicAdd(&hacc[(size_t)prev * DN + cA], run0);
    atomicAdd(&hacc[(size_t)prev * DN + cA + 1], run1);
    int slice = ((blockIdx.x & 7) << 1) | (w & 1);
    atomicAdd(&colsum16[slice * DN + cA], cs0);
    atomicAdd(&colsum16[slice * DN + cA + 1], cs1);
  }
}

// ---------- final (R5 structure): h = mish(concat[node_feat, hacc/colsum] @ Wn1 + bn1) @ Wn2 + bn2 ----------
__global__ __launch_bounds__(256, 2)
void final_h(const float* __restrict__ nodef,
             const float* __restrict__ hacc,
             const float* __restrict__ colsum16,
             const us* __restrict__ Wn1T,
             const float* __restrict__ bn1,
             const us* __restrict__ Wn2T,
             const float* __restrict__ bn2,
             float* __restrict__ outh)
{
  __shared__ us Ash[64 * 256];   // [64 rows][256 cols] bf16, stride 512B
  __shared__ float rcs[DN];      // 1/colsum per column

  const int tid = threadIdx.x;
  const int r0 = blockIdx.x * 64;

  if (tid < DN){
    float ssum = 0.f;
#pragma unroll
    for (int x = 0; x < 16; ++x) ssum += colsum16[x * DN + tid];
    rcs[tid] = 1.f / ssum;
  }
  __syncthreads();

  { // stage node_feat -> cols 0..127, hacc*rcs -> cols 128..255
    int r = tid >> 2, c4 = tid & 3;
    int grow = r0 + r; if (grow >= NND) grow = NND - 1;
    const f4* np = (const f4*)(nodef + (size_t)grow * DN + c4 * 32);
    const f4* hp = (const f4*)(hacc + (size_t)grow * DN + c4 * 32);
#pragma unroll
    for (int j = 0; j < 4; ++j){
      f4 v0 = np[2*j], v1 = np[2*j+1];
      bf8 o;
#pragma unroll
      for (int q = 0; q < 4; ++q){ o[q] = (short)f2bf(v0[q]); o[4+q] = (short)f2bf(v1[q]); }
      int byte = r*512 + c4*64 + j*16; byte ^= (r & 7) << 4;
      *(bf8*)((char*)Ash + byte) = o;
      f4 h0 = hp[2*j], h1 = hp[2*j+1];
      bf8 o2;
#pragma unroll
      for (int q = 0; q < 4; ++q){
        o2[q]   = (short)f2bf(h0[q] * rcs[c4*32 + j*8 + q]);
        o2[4+q] = (short)f2bf(h1[q] * rcs[c4*32 + j*8 + 4 + q]);
      }
      int byte2 = r*512 + 256 + c4*64 + j*16; byte2 ^= (r & 7) << 4;
      *(bf8*)((char*)Ash + byte2) = o2;
    }
  }
  __syncthreads();

  const int lane = tid & 63, w = tid >> 6;
  const int wr = w >> 1, wc = w & 1;
  const int g = lane >> 4, s = lane & 15;

  float b1v[4], b2v[4];
#pragma unroll
  for (int ct = 0; ct < 4; ++ct){ int n = wc*64 + ct*16 + s; b1v[ct] = bn1[n]; b2v[ct] = bn2[n]; }

  f4 acc[2][4];
#pragma unroll
  for (int ct = 0; ct < 4; ++ct){ f4 t = {b1v[ct], b1v[ct], b1v[ct], b1v[ct]}; acc[0][ct] = t; acc[1][ct] = t; }

  bf8 a[2][8];
#pragma unroll
  for (int rt = 0; rt < 2; ++rt)
#pragma unroll
    for (int kk = 0; kk < 8; ++kk)
      a[rt][kk] = lds_frag(Ash, wr*32 + rt*16 + s, 512, kk*32 + g*8);
  __syncthreads();   // frag reads done -> Ash reusable as T

#pragma unroll
  for (int ct = 0; ct < 4; ++ct){
    int n = wc*64 + ct*16 + s;
#pragma unroll
    for (int kk = 0; kk < 8; ++kk){
      bf8 b = gfrag(Wn1T, n, 256, kk*32 + g*8);
      acc[0][ct] = MFMA16(a[0][kk], b, acc[0][ct]);
      acc[1][ct] = MFMA16(a[1][kk], b, acc[1][ct]);
    }
  }

#pragma unroll
  for (int rt = 0; rt < 2; ++rt)
#pragma unroll
    for (int ct = 0; ct < 4; ++ct)
#pragma unroll
      for (int reg = 0; reg < 4; ++reg)
        acc[rt][ct][reg] = mishf(acc[rt][ct][reg]);
  write_T((us*)Ash, wr, wc, g, s, acc);
  __syncthreads();

  f4 acc2[2][4];
#pragma unroll
  for (int ct = 0; ct < 4; ++ct){ f4 t = {b2v[ct], b2v[ct], b2v[ct], b2v[ct]}; acc2[0][ct] = t; acc2[1][ct] = t; }
  bf8 a2[2][4];
  load_a2((const us*)Ash, wr, g, s, a2);
#pragma unroll
  for (int ct = 0; ct < 4; ++ct){
    int n = wc*64 + ct*16 + s;
#pragma unroll
    for (int kk = 0; kk < 4; ++kk){
      bf8 b = gfrag(Wn2T, n, DN, kk*32 + g*8);
      acc2[0][ct] = MFMA16(a2[0][kk], b, acc2[0][ct]);
      acc2[1][ct] = MFMA16(a2[1][kk], b, acc2[1][ct]);
    }
  }
  store_tile<0>((void*)outh, NND, r0, wr, wc, g, s, DN, acc2);
}

struct WPrepArgs {
  const float* w[12];
  us* wt[12];
  int K[12];
};

// W^T bf16: wt[n*K + k] = bf16(W[k*128 + n])
__global__ void prep_weights(WPrepArgs a){
  int widx = blockIdx.y;
  int K = a.K[widx];
  int idx = blockIdx.x * 256 + threadIdx.x;
  if (idx >= DN * K) return;
  int kshift = (K == 256) ? 8 : 7;
  int n = idx >> kshift;
  int k = idx & (K - 1);
  a.wt[widx][idx] = f2bf(a.w[widx][(size_t)k * DN + n]);
}

extern "C" void kernel_launch(void* const* d_in, const int* in_sizes, int n_in,
                              void* d_out, int out_size, void* d_ws, size_t ws_size,
                              hipStream_t stream) {
  const float* node_feat = (const float*)d_in[0];
  const float* coordf    = (const float*)d_in[1];
  const float* Wq  = (const float*)d_in[2];
  const float* bq  = (const float*)d_in[3];
  const float* gq  = (const float*)d_in[4];
  const float* beq = (const float*)d_in[5];
  const float* Wk  = (const float*)d_in[6];
  const float* bk  = (const float*)d_in[7];
  const float* gk  = (const float*)d_in[8];
  const float* bek = (const float*)d_in[9];
  const float* Wm1 = (const float*)d_in[10];
  const float* bm1 = (const float*)d_in[11];
  const float* gm  = (const float*)d_in[12];
  const float* bem = (const float*)d_in[13];
  const float* Wm2 = (const float*)d_in[14];
  const float* bm2 = (const float*)d_in[15];
  const float* Wb1 = (const float*)d_in[16];
  const float* bb1 = (const float*)d_in[17];
  const float* gb  = (const float*)d_in[18];
  const float* beb = (const float*)d_in[19];
  const float* Wb2 = (const float*)d_in[20];
  const float* bb2 = (const float*)d_in[21];
  const float* Ww1 = (const float*)d_in[22];
  const float* bw1 = (const float*)d_in[23];
  const float* gw  = (const float*)d_in[24];
  const float* bew = (const float*)d_in[25];
  const float* Ww2 = (const float*)d_in[26];
  const float* bw2 = (const float*)d_in[27];
  const float* Wn1 = (const float*)d_in[28];
  const float* bn1 = (const float*)d_in[29];
  const float* Wn2 = (const float*)d_in[30];
  const float* bn2 = (const float*)d_in[31];
  const float* Wc1 = (const float*)d_in[32];
  const float* bc1 = (const float*)d_in[33];
  const float* Wc2 = (const float*)d_in[34];
  const int* srcI  = (const int*)d_in[35];
  const int* dstI  = (const int*)d_in[36];

  char* ws = (char*)d_ws;
  size_t off = 0;
  auto alloc = [&](size_t bytes) -> char* {
    char* p = ws + off;
    off += (bytes + 255) & ~(size_t)255;
    return p;
  };
  us*    qt       = (us*)alloc((size_t)NND * DN * 2);
  us*    kmb      = (us*)alloc((size_t)NND * 384 * 2);
  float* hacc     = (float*)alloc((size_t)NND * DN * 4);
  float* colsum16 = (float*)alloc(16 * DN * 4);
  int*   deg      = (int*)alloc((size_t)NND * 4);
  int*   fillctr  = (int*)alloc((size_t)NND * 4);
  int*   ssorted  = (int*)alloc((size_t)NED * 4);
  int*   dsorted  = (int*)alloc((size_t)NED * 4);
  int*   bsum     = (int*)alloc((size_t)NSCAN * 4);
  int*   boff     = (int*)alloc((size_t)NSCAN * 4);
  us*    wtb      = (us*)alloc((size_t)13 * 16384 * 2);   // 11 K=128 + 1 K=256 (2 slots)

  // zero the atomic accumulators (hacc + colsum16 are adjacent)
  hipMemsetAsync(hacc, 0, (size_t)NND * DN * 4 + 16 * DN * 4, stream);
  hipMemsetAsync(deg, 0, (size_t)NND * 4, stream);

  WPrepArgs pa;
  const float* wsrc[12] = {Wq, Wk, Wm1, Wm2, Wb1, Wb2, Ww1, Ww2, Wc1, Wc2, Wn2, Wn1};
  for (int i = 0; i < 12; ++i){
    pa.w[i] = wsrc[i];
    pa.wt[i] = wtb + (size_t)i * 16384;
    pa.K[i] = (i == 11) ? 256 : 128;
  }
  prep_weights<<<dim3(128, 12), 256, 0, stream>>>(pa);

  // CSR positions + edge sort by dst
  csr_count<<<(NED + 255) / 256, 256, 0, stream>>>(dstI, deg);
  csr_blocksum<<<NSCAN, 1024, 0, stream>>>(deg, bsum);
  csr_scanroot<<<1, 64, 0, stream>>>(bsum, boff);
  csr_scatter<<<NSCAN, 1024, 0, stream>>>(deg, boff, fillctr);
  csr_fill<<<(NED + 255) / 256, 256, 0, stream>>>(srcI, dstI, fillctr, ssorted, dsorted);

  const int NB = (NND + 63) / 64;  // 782

  node_fused<<<NB, 256, 0, stream>>>(coordf,
      pa.wt[0], bq, gq, beq,
      pa.wt[1], bk, gk, bek,
      pa.wt[2], bm1, gm, bem, pa.wt[3], bm2,
      pa.wt[4], bb1, gb, beb, pa.wt[5], bb2,
      pa.wt[8], bc1, pa.wt[9],
      qt, kmb, (float*)d_out + (size_t)NND * DN);

  edge_kernel<<<NED / 128, 256, 0, stream>>>(qt, kmb, pa.wt[6], pa.wt[7],
                                             bw1, gw, bew, bw2, ssorted, dsorted,
                                             hacc, colsum16);

  final_h<<<NB, 256, 0, stream>>>(node_feat, hacc, colsum16,
                                  pa.wt[11], bn1, pa.wt[10], bn2, (float*)d_out);
}

// Round 13
// 517.295 us; speedup vs baseline: 1.4271x; 1.0093x over previous
//
#include <hip/hip_runtime.h>
#include <cstdint>
#include <cstddef>

#define DN 128
#define NND 50000
#define NED 512000
#define NSCAN 49   // ceil(NND/1024)

typedef __attribute__((ext_vector_type(8))) short bf8;
typedef __attribute__((ext_vector_type(4))) float f4;
typedef unsigned short us;

__device__ __forceinline__ us f2bf(float f){
  union { float f; unsigned int u; } c; c.f = f;
  unsigned int r = c.u + 0x7fffu + ((c.u >> 16) & 1u);
  return (us)(r >> 16);
}
__device__ __forceinline__ float bf2f(us u){
  union { unsigned int u; float f; } c; c.u = ((unsigned int)u) << 16;
  return c.f;
}
// mish(x) = x*tanh(softplus(x)) = x*(u^2-1)/(u^2+1), u = 1+exp(x)
__device__ __forceinline__ float mishf(float x){
  float e = __expf(x);
  float u = 1.f + e;
  float u2 = u * u;
  float t = __fdividef(u2 - 1.f, u2 + 1.f);
  return x * ((x > 20.f) ? 1.f : t);
}

#define MFMA16(a, b, c) __builtin_amdgcn_mfma_f32_16x16x32_bf16((a), (b), (c), 0, 0, 0)

// LDS fragment read: row-major [rows][K] bf16 with (row&7)<<4 byte XOR swizzle.
__device__ __forceinline__ bf8 lds_frag(const us* base, int row, int rowStrideB, int kElem){
  int byte = row * rowStrideB + kElem * 2;
  byte ^= (row & 7) << 4;
  return *(const bf8*)((const char*)base + byte);
}
// Global weight fragment: W^T stored [Nout][K] bf16, plain row-major.
__device__ __forceinline__ bf8 gfrag(const us* W, int n, int K, int kElem){
  return *(const bf8*)(W + (size_t)n * K + kElem);
}

template<int OUT_BF16>
__device__ __forceinline__ void store_tile(void* outp, int nrows, int r0,
                                           int wr, int wc, int g, int s, int ostride,
                                           const f4 (&A)[2][4]){
#pragma unroll
  for (int rt = 0; rt < 2; ++rt)
#pragma unroll
    for (int ct = 0; ct < 4; ++ct)
#pragma unroll
      for (int reg = 0; reg < 4; ++reg){
        int row = r0 + wr*32 + rt*16 + g*4 + reg;
        if (row < nrows){
          int col = wc*64 + ct*16 + s;
          float v = A[rt][ct][reg];
          if constexpr (OUT_BF16 != 0)
            ((us*)outp)[(size_t)row*ostride + col] = f2bf(v);
          else
            ((float*)outp)[(size_t)row*ostride + col] = v;
        }
      }
}

// GEMM: acc = bias + A(regs) @ W^T  (2 row-frags x 4 col-frags; 2x B reuse)
__device__ __forceinline__ void gemm_reg(const bf8 (&a)[2][4], const us* __restrict__ WT,
                                         const float* __restrict__ bias,
                                         int wc, int g, int s, f4 (&acc)[2][4]){
#pragma unroll
  for (int ct = 0; ct < 4; ++ct){
    float bv = bias ? bias[wc*64 + ct*16 + s] : 0.f;
    f4 t = {bv, bv, bv, bv};
    acc[0][ct] = t; acc[1][ct] = t;
  }
#pragma unroll
  for (int ct = 0; ct < 4; ++ct){
    int n = wc*64 + ct*16 + s;
#pragma unroll
    for (int kk = 0; kk < 4; ++kk){
      bf8 b = gfrag(WT, n, DN, kk*32 + g*8);
      acc[0][ct] = MFMA16(a[0][kk], b, acc[0][ct]);
      acc[1][ct] = MFMA16(a[1][kk], b, acc[1][ct]);
    }
  }
}

// LN across the 128-wide row (two waves share a row) + mish. Uses buf parity to
// avoid WAR races on the stats arrays between consecutive chains.
__device__ __forceinline__ void ln_mish(f4 (&acc)[2][4],
                                        const float* __restrict__ gam,
                                        const float* __restrict__ bet,
                                        int wr, int wc, int g, int s,
                                        float (*rowsum)[64][2], float (*rowsq)[64][2],
                                        int buf){
  float gv[4], bev[4];
#pragma unroll
  for (int ct = 0; ct < 4; ++ct){ int n = wc*64 + ct*16 + s; gv[ct] = gam[n]; bev[ct] = bet[n]; }
#pragma unroll
  for (int rt = 0; rt < 2; ++rt)
#pragma unroll
    for (int reg = 0; reg < 4; ++reg){
      float sm = acc[rt][0][reg] + acc[rt][1][reg] + acc[rt][2][reg] + acc[rt][3][reg];
      float sq = acc[rt][0][reg]*acc[rt][0][reg] + acc[rt][1][reg]*acc[rt][1][reg]
               + acc[rt][2][reg]*acc[rt][2][reg] + acc[rt][3][reg]*acc[rt][3][reg];
#pragma unroll
      for (int m = 1; m < 16; m <<= 1){ sm += __shfl_xor(sm, m, 64); sq += __shfl_xor(sq, m, 64); }
      if (s == 0){
        int row = wr*32 + rt*16 + g*4 + reg;
        rowsum[buf][row][wc] = sm; rowsq[buf][row][wc] = sq;
      }
    }
  __syncthreads();
#pragma unroll
  for (int rt = 0; rt < 2; ++rt)
#pragma unroll
    for (int reg = 0; reg < 4; ++reg){
      int row = wr*32 + rt*16 + g*4 + reg;
      float sm = rowsum[buf][row][0] + rowsum[buf][row][1];
      float sq = rowsq[buf][row][0] + rowsq[buf][row][1];
      float mu = sm * (1.f/128.f);
      float var = sq * (1.f/128.f) - mu*mu;
      float rs = rsqrtf(var + 1e-5f);
#pragma unroll
      for (int ct = 0; ct < 4; ++ct)
        acc[rt][ct][reg] = mishf((acc[rt][ct][reg] - mu) * rs * gv[ct] + bev[ct]);
    }
}

__device__ __forceinline__ void write_T(us* Tsh, int wr, int wc, int g, int s,
                                        const f4 (&A)[2][4]){
#pragma unroll
  for (int rt = 0; rt < 2; ++rt)
#pragma unroll
    for (int ct = 0; ct < 4; ++ct)
#pragma unroll
      for (int reg = 0; reg < 4; ++reg){
        int row = wr*32 + rt*16 + g*4 + reg;
        int col = wc*64 + ct*16 + s;
        int byte = row*256 + col*2; byte ^= (row & 7) << 4;
        *(us*)((char*)Tsh + byte) = f2bf(A[rt][ct][reg]);
      }
}

__device__ __forceinline__ void load_a2(const us* Tsh, int wr, int g, int s, bf8 (&a2)[2][4]){
#pragma unroll
  for (int rt = 0; rt < 2; ++rt)
#pragma unroll
    for (int kk = 0; kk < 4; ++kk)
      a2[rt][kk] = lds_frag(Tsh, wr*32 + rt*16 + s, 256, kk*32 + g*8);
}

// ---- wave-local 32-row x 128-col primitives (edge kernel; zero cross-wave sync) ----
__device__ __forceinline__ void loadA32(const us* T, int g, int s, bf8 (&a)[2][4]){
#pragma unroll
  for (int rt = 0; rt < 2; ++rt)
#pragma unroll
    for (int kk = 0; kk < 4; ++kk)
      a[rt][kk] = lds_frag(T, rt*16 + s, 256, kk*32 + g*8);
}

__device__ __forceinline__ void gemm32(const bf8 (&a)[2][4], const us* __restrict__ WT,
                                       const float* __restrict__ bias,
                                       int g, int s, f4 (&acc)[2][8]){
#pragma unroll
  for (int ct = 0; ct < 8; ++ct){
    float bv = bias ? bias[ct*16 + s] : 0.f;
    f4 t = {bv, bv, bv, bv};
    acc[0][ct] = t; acc[1][ct] = t;
  }
#pragma unroll
  for (int ct = 0; ct < 8; ++ct){
    int n = ct*16 + s;
#pragma unroll
    for (int kk = 0; kk < 4; ++kk){
      bf8 b = gfrag(WT, n, DN, kk*32 + g*8);
      acc[0][ct] = MFMA16(a[0][kk], b, acc[0][ct]);
      acc[1][ct] = MFMA16(a[1][kk], b, acc[1][ct]);
    }
  }
}

// LayerNorm over the 128-wide row fully in-wave + mish.
__device__ __forceinline__ void ln_mish32(f4 (&acc)[2][8],
                                          const float* __restrict__ gam,
                                          const float* __restrict__ bet, int s){
#pragma unroll
  for (int rt = 0; rt < 2; ++rt){
    float mu[4], rs[4];
#pragma unroll
    for (int reg = 0; reg < 4; ++reg){
      float sm = 0.f, sq = 0.f;
#pragma unroll
      for (int ct = 0; ct < 8; ++ct){ float v = acc[rt][ct][reg]; sm += v; sq += v*v; }
#pragma unroll
      for (int m = 1; m < 16; m <<= 1){ sm += __shfl_xor(sm, m, 64); sq += __shfl_xor(sq, m, 64); }
      float mm = sm * (1.f/128.f);
      float var = sq * (1.f/128.f) - mm*mm;
      mu[reg] = mm; rs[reg] = rsqrtf(var + 1e-5f);
    }
#pragma unroll
    for (int ct = 0; ct < 8; ++ct){
      float gv = gam[ct*16 + s], bv = bet[ct*16 + s];
#pragma unroll
      for (int reg = 0; reg < 4; ++reg)
        acc[rt][ct][reg] = mishf((acc[rt][ct][reg] - mu[reg]) * rs[reg] * gv + bv);
    }
  }
}

__device__ __forceinline__ void writeT32(us* T, int g, int s, const f4 (&A)[2][8]){
#pragma unroll
  for (int rt = 0; rt < 2; ++rt)
#pragma unroll
    for (int ct = 0; ct < 8; ++ct)
#pragma unroll
      for (int reg = 0; reg < 4; ++reg){
        int row = rt*16 + g*4 + reg, col = ct*16 + s;
        int byte = row*256 + col*2; byte ^= (row & 7) << 4;
        *(us*)((char*)T + byte) = f2bf(A[rt][ct][reg]);
      }
}

// ---------- Fused node chains (R5 structure: 64-row block, 2x2 waves, 2x B reuse) ----------
__global__ __launch_bounds__(256, 2)
void node_fused(const float* __restrict__ X,
                const us* __restrict__ WqT,  const float* __restrict__ bq,
                const float* __restrict__ gq, const float* __restrict__ beq,
                const us* __restrict__ WkT,  const float* __restrict__ bk,
                const float* __restrict__ gk, const float* __restrict__ bek,
                const us* __restrict__ Wm1T, const float* __restrict__ bm1,
                const float* __restrict__ gm, const float* __restrict__ bem,
                const us* __restrict__ Wm2T, const float* __restrict__ bm2,
                const us* __restrict__ Wb1T, const float* __restrict__ bb1,
                const float* __restrict__ gb, const float* __restrict__ beb,
                const us* __restrict__ Wb2T, const float* __restrict__ bb2,
                const us* __restrict__ Wc1T, const float* __restrict__ bc1,
                const us* __restrict__ Wc2T,
                us* __restrict__ qt, us* __restrict__ kmb, float* __restrict__ xout)
{
  __shared__ us Ash[64 * DN];
  __shared__ float rowsum[2][64][2];
  __shared__ float rowsq[2][64][2];

  const int tid = threadIdx.x;
  const int r0 = blockIdx.x * 64;

  { // stage X rows -> bf16 swizzled LDS (once, shared by 8 GEMMs)
    int r = tid >> 2, c4 = tid & 3;
    int grow = r0 + r; if (grow >= NND) grow = NND - 1;
    const f4* sp = (const f4*)(X + (size_t)grow * DN + c4 * 32);
#pragma unroll
    for (int j = 0; j < 4; ++j){
      f4 v0 = sp[2*j], v1 = sp[2*j+1];
      bf8 o;
#pragma unroll
      for (int q = 0; q < 4; ++q){ o[q] = (short)f2bf(v0[q]); o[4+q] = (short)f2bf(v1[q]); }
      int byte = r*256 + c4*64 + j*16; byte ^= (r & 7) << 4;
      *(bf8*)((char*)Ash + byte) = o;
    }
  }
  __syncthreads();

  const int lane = tid & 63, w = tid >> 6;
  const int wr = w >> 1, wc = w & 1;
  const int g = lane >> 4, s = lane & 15;

  bf8 a[2][4];
#pragma unroll
  for (int rt = 0; rt < 2; ++rt)
#pragma unroll
    for (int kk = 0; kk < 4; ++kk)
      a[rt][kk] = lds_frag(Ash, wr*32 + rt*16 + s, 256, kk*32 + g*8);
  __syncthreads();   // all A-frag reads done -> Ash reusable as T

  f4 acc[2][4], acc2[2][4];
  bf8 a2[2][4];

  // ---- q ----
  gemm_reg(a, WqT, bq, wc, g, s, acc);
  ln_mish(acc, gq, beq, wr, wc, g, s, rowsum, rowsq, 0);
  store_tile<1>((void*)qt, NND, r0, wr, wc, g, s, DN, acc);

  // ---- k ----
  gemm_reg(a, WkT, bk, wc, g, s, acc);
  ln_mish(acc, gk, bek, wr, wc, g, s, rowsum, rowsq, 1);
  store_tile<1>((void*)kmb, NND, r0, wr, wc, g, s, 384, acc);

  // ---- m (2 GEMM) ----
  gemm_reg(a, Wm1T, bm1, wc, g, s, acc);
  ln_mish(acc, gm, bem, wr, wc, g, s, rowsum, rowsq, 0);
  write_T(Ash, wr, wc, g, s, acc);
  __syncthreads();
  load_a2(Ash, wr, g, s, a2);
#pragma unroll
  for (int ct = 0; ct < 4; ++ct){
    float bv = bm2[wc*64 + ct*16 + s]; f4 t = {bv,bv,bv,bv}; acc2[0][ct] = t; acc2[1][ct] = t;
  }
#pragma unroll
  for (int ct = 0; ct < 4; ++ct){
    int n = wc*64 + ct*16 + s;
#pragma unroll
    for (int kk = 0; kk < 4; ++kk){
      bf8 b = gfrag(Wm2T, n, DN, kk*32 + g*8);
      acc2[0][ct] = MFMA16(a2[0][kk], b, acc2[0][ct]);
      acc2[1][ct] = MFMA16(a2[1][kk], b, acc2[1][ct]);
    }
  }
  store_tile<1>((void*)(kmb + 128), NND, r0, wr, wc, g, s, 384, acc2);

  // ---- b (2 GEMM) ----
  gemm_reg(a, Wb1T, bb1, wc, g, s, acc);
  ln_mish(acc, gb, beb, wr, wc, g, s, rowsum, rowsq, 1);
  write_T(Ash, wr, wc, g, s, acc);
  __syncthreads();
  load_a2(Ash, wr, g, s, a2);
#pragma unroll
  for (int ct = 0; ct < 4; ++ct){
    float bv = bb2[wc*64 + ct*16 + s]; f4 t = {bv,bv,bv,bv}; acc2[0][ct] = t; acc2[1][ct] = t;
  }
#pragma unroll
  for (int ct = 0; ct < 4; ++ct){
    int n = wc*64 + ct*16 + s;
#pragma unroll
    for (int kk = 0; kk < 4; ++kk){
      bf8 b = gfrag(Wb2T, n, DN, kk*32 + g*8);
      acc2[0][ct] = MFMA16(a2[0][kk], b, acc2[0][ct]);
      acc2[1][ct] = MFMA16(a2[1][kk], b, acc2[1][ct]);
    }
  }
  store_tile<1>((void*)(kmb + 256), NND, r0, wr, wc, g, s, 384, acc2);

  // ---- c (2 GEMM, no LN) ----
  gemm_reg(a, Wc1T, bc1, wc, g, s, acc);
#pragma unroll
  for (int rt = 0; rt < 2; ++rt)
#pragma unroll
    for (int ct = 0; ct < 4; ++ct)
#pragma unroll
      for (int reg = 0; reg < 4; ++reg)
        acc[rt][ct][reg] = mishf(acc[rt][ct][reg]);
  __syncthreads();
  write_T(Ash, wr, wc, g, s, acc);
  __syncthreads();
  load_a2(Ash, wr, g, s, a2);
#pragma unroll
  for (int ct = 0; ct < 4; ++ct){ f4 t = {0,0,0,0}; acc2[0][ct] = t; acc2[1][ct] = t; }
#pragma unroll
  for (int ct = 0; ct < 4; ++ct){
    int n = wc*64 + ct*16 + s;
#pragma unroll
    for (int kk = 0; kk < 4; ++kk){
      bf8 b = gfrag(Wc2T, n, DN, kk*32 + g*8);
      acc2[0][ct] = MFMA16(a2[0][kk], b, acc2[0][ct]);
      acc2[1][ct] = MFMA16(a2[1][kk], b, acc2[1][ct]);
    }
  }
  store_tile<0>((void*)xout, NND, r0, wr, wc, g, s, DN, acc2);
}

// ---------- CSR build ----------
__global__ void csr_count(const int* __restrict__ dst, int* __restrict__ deg){
  int e = blockIdx.x * 256 + threadIdx.x;
  if (e < NED) atomicAdd(&deg[dst[e]], 1);
}

__global__ __launch_bounds__(1024) void csr_blocksum(const int* __restrict__ deg,
                                                     int* __restrict__ bsum){
  __shared__ int sb[1024];
  int t = threadIdx.x, idx = blockIdx.x * 1024 + t;
  sb[t] = (idx < NND) ? deg[idx] : 0;
  __syncthreads();
  for (int off = 512; off > 0; off >>= 1){
    if (t < off) sb[t] += sb[t + off];
    __syncthreads();
  }
  if (t == 0) bsum[blockIdx.x] = sb[0];
}

__global__ void csr_scanroot(const int* __restrict__ bsum, int* __restrict__ boff){
  if (threadIdx.x == 0){
    int run = 0;
    for (int b = 0; b < NSCAN; ++b){ boff[b] = run; run += bsum[b]; }
  }
}

__global__ __launch_bounds__(1024) void csr_scatter(const int* __restrict__ deg,
                                                    const int* __restrict__ boff,
                                                    int* __restrict__ fillctr){
  __shared__ int ss[1024];
  int t = threadIdx.x, idx = blockIdx.x * 1024 + t;
  int v = (idx < NND) ? deg[idx] : 0;
  ss[t] = v;
  __syncthreads();
  for (int off = 1; off < 1024; off <<= 1){
    int x = (t >= off) ? ss[t - off] : 0;
    __syncthreads();
    ss[t] += x;
    __syncthreads();
  }
  if (idx < NND){
    int p = boff[blockIdx.x] + ss[t] - v;
    fillctr[idx] = p;
  }
}

__global__ void csr_fill(const int* __restrict__ src, const int* __restrict__ dst,
                         int* __restrict__ fillctr,
                         int* __restrict__ ssorted, int* __restrict__ dsorted){
  int e = blockIdx.x * 256 + threadIdx.x;
  if (e < NED){
    int d = dst[e];
    int p = atomicAdd(&fillctr[d], 1);
    ssorted[p] = src[e];
    dsorted[p] = d;
  }
}

// ---------- Edge pass: 256-thread blocks, 4 waves x 32 sorted edges, zero
// barriers, 2x B-reuse, wave-local segment-sum. R13 change vs R12: BOTH
// 16-row halves are staged into disjoint register sets so all 48 gather
// loads issue before any s_waitcnt -> one HBM latency per tile, not two. ----------
__global__ __launch_bounds__(256, 2)
void edge_kernel(const us* __restrict__ qtab,
                 const us* __restrict__ kmb,   // [N][384]: k|m|b
                 const us* __restrict__ W1T,
                 const us* __restrict__ W2T,
                 const float* __restrict__ bw1,
                 const float* __restrict__ gwp,
                 const float* __restrict__ bewp,
                 const float* __restrict__ bw2,
                 const int* __restrict__ ssorted,
                 const int* __restrict__ dsorted,
                 float* __restrict__ hacc,      // [N][128] f32, atomic accumulate
                 float* __restrict__ colsum16)  // [16][128] f32 slices
{
  __shared__ us Tsh[4][32 * DN];   // per-wave tile: rel -> t -> p
  __shared__ int dsh[4][32];

  const int tid = threadIdx.x;
  const int lane = tid & 63, w = tid >> 6;
  const int g = lane >> 4, s = lane & 15;
  const int r = lane >> 2, c4 = lane & 3;

  // XCD-chunked swizzle (concurrent blocks cover a narrow sorted window)
  const int nchunk = gridDim.x >> 3;
  const int swz = (blockIdx.x & 7) * nchunk + (blockIdx.x >> 3);
  const int e0w = swz * 128 + w * 32;
  us* T = (us*)Tsh[w];
  int* dloc = dsh[w];

  // ---- full-tile gather: issue ALL loads before any rel math ----
  bf8 qv[2][4], kv[2][4], mv[2][4], bv[2][4];
  int sn[2], dn[2];
#pragma unroll
  for (int hh = 0; hh < 2; ++hh){
    int e = e0w + hh*16 + r;
    sn[hh] = ssorted[e];
    dn[hh] = dsorted[e];
  }
#pragma unroll
  for (int hh = 0; hh < 2; ++hh){
    const bf8* qp = (const bf8*)(qtab + (size_t)sn[hh] * DN + c4 * 32);
    const us*  kb = kmb + (size_t)dn[hh] * 384 + c4 * 32;
#pragma unroll
    for (int j = 0; j < 4; ++j){
      qv[hh][j] = qp[j];
      kv[hh][j] = *(const bf8*)(kb + j*8);
      mv[hh][j] = *(const bf8*)(kb + 128 + j*8);
      bv[hh][j] = *(const bf8*)(kb + 256 + j*8);
    }
    if (c4 == 0) dloc[hh*16 + r] = dn[hh];
  }

  // ---- rel for both halves ----
#pragma unroll
  for (int hh = 0; hh < 2; ++hh){
    float ss = 0.f;
#pragma unroll
    for (int j = 0; j < 4; ++j)
#pragma unroll
      for (int q = 0; q < 8; ++q){
        float d = bf2f((us)qv[hh][j][q]) - bf2f((us)kv[hh][j][q]);
        ss += d * d;
      }
    ss += __shfl_xor(ss, 1, 64);
    ss += __shfl_xor(ss, 2, 64);
    float rinv = rsqrtf(ss + 1e-8f);

    int lrow = hh*16 + r;
#pragma unroll
    for (int j = 0; j < 4; ++j){
      bf8 o;
#pragma unroll
      for (int q = 0; q < 8; ++q){
        float d = bf2f((us)qv[hh][j][q]) - bf2f((us)kv[hh][j][q]);
        float v = d * rinv * bf2f((us)mv[hh][j][q]) + bf2f((us)bv[hh][j][q]);
        o[q] = (short)f2bf(v);
      }
      int byte = lrow*256 + c4*64 + j*16; byte ^= (lrow & 7) << 4;
      *(bf8*)((char*)T + byte) = o;
    }
  }

  // GEMM1 -> in-wave LN+mish -> GEMM2 (acc reused) -> exp
  bf8 a[2][4];
  loadA32(T, g, s, a);
  f4 acc[2][8];
  gemm32(a, W1T, bw1, g, s, acc);
  ln_mish32(acc, gwp, bewp, s);
  writeT32(T, g, s, acc);
  bf8 a2[2][4];
  loadA32(T, g, s, a2);
  gemm32(a2, W2T, bw2, g, s, acc);
#pragma unroll
  for (int rt = 0; rt < 2; ++rt)
#pragma unroll
    for (int ct = 0; ct < 8; ++ct)
#pragma unroll
      for (int reg = 0; reg < 4; ++reg)
        acc[rt][ct][reg] = __expf(acc[rt][ct][reg]);

  // p -> wave tile (in-wave LDS ordering; no barrier needed)
  writeT32(T, g, s, acc);

  { // wave-local segment-sum: lane owns cols (2*lane, 2*lane+1), walks 32 sorted rows
    int cA = lane * 2;
    float run0 = 0.f, run1 = 0.f, cs0 = 0.f, cs1 = 0.f;
    int prev = dloc[0];
#pragma unroll 8
    for (int r2 = 0; r2 < 32; ++r2){
      int byte = r2*256 + cA*2; byte ^= (r2 & 7) << 4;
      unsigned int v = *(const unsigned int*)((const char*)T + byte);
      float f0 = bf2f((us)(v & 0xffffu));
      float f1 = bf2f((us)(v >> 16));
      int d = dloc[r2];
      cs0 += f0; cs1 += f1;
      if (d != prev){
        atomicAdd(&hacc[(size_t)prev * DN + cA], run0);
        atomicAdd(&hacc[(size_t)prev * DN + cA + 1], run1);
        run0 = f0; run1 = f1; prev = d;
      } else {
        run0 += f0; run1 += f1;
      }
    }
    atomicAdd(&hacc[(size_t)prev * DN + cA], run0);
    atomicAdd(&hacc[(size_t)prev * DN + cA + 1], run1);
    int slice = ((blockIdx.x & 7) << 1) | (w & 1);
    atomicAdd(&colsum16[slice * DN + cA], cs0);
    atomicAdd(&colsum16[slice * DN + cA + 1], cs1);
  }
}

// ---------- final (R5 structure): h = mish(concat[node_feat, hacc/colsum] @ Wn1 + bn1) @ Wn2 + bn2 ----------
__global__ __launch_bounds__(256, 2)
void final_h(const float* __restrict__ nodef,
             const float* __restrict__ hacc,
             const float* __restrict__ colsum16,
             const us* __restrict__ Wn1T,
             const float* __restrict__ bn1,
             const us* __restrict__ Wn2T,
             const float* __restrict__ bn2,
             float* __restrict__ outh)
{
  __shared__ us Ash[64 * 256];   // [64 rows][256 cols] bf16, stride 512B
  __shared__ float rcs[DN];      // 1/colsum per column

  const int tid = threadIdx.x;
  const int r0 = blockIdx.x * 64;

  if (tid < DN){
    float ssum = 0.f;
#pragma unroll
    for (int x = 0; x < 16; ++x) ssum += colsum16[x * DN + tid];
    rcs[tid] = 1.f / ssum;
  }
  __syncthreads();

  { // stage node_feat -> cols 0..127, hacc*rcs -> cols 128..255
    int r = tid >> 2, c4 = tid & 3;
    int grow = r0 + r; if (grow >= NND) grow = NND - 1;
    const f4* np = (const f4*)(nodef + (size_t)grow * DN + c4 * 32);
    const f4* hp = (const f4*)(hacc + (size_t)grow * DN + c4 * 32);
#pragma unroll
    for (int j = 0; j < 4; ++j){
      f4 v0 = np[2*j], v1 = np[2*j+1];
      bf8 o;
#pragma unroll
      for (int q = 0; q < 4; ++q){ o[q] = (short)f2bf(v0[q]); o[4+q] = (short)f2bf(v1[q]); }
      int byte = r*512 + c4*64 + j*16; byte ^= (r & 7) << 4;
      *(bf8*)((char*)Ash + byte) = o;
      f4 h0 = hp[2*j], h1 = hp[2*j+1];
      bf8 o2;
#pragma unroll
      for (int q = 0; q < 4; ++q){
        o2[q]   = (short)f2bf(h0[q] * rcs[c4*32 + j*8 + q]);
        o2[4+q] = (short)f2bf(h1[q] * rcs[c4*32 + j*8 + 4 + q]);
      }
      int byte2 = r*512 + 256 + c4*64 + j*16; byte2 ^= (r & 7) << 4;
      *(bf8*)((char*)Ash + byte2) = o2;
    }
  }
  __syncthreads();

  const int lane = tid & 63, w = tid >> 6;
  const int wr = w >> 1, wc = w & 1;
  const int g = lane >> 4, s = lane & 15;

  float b1v[4], b2v[4];
#pragma unroll
  for (int ct = 0; ct < 4; ++ct){ int n = wc*64 + ct*16 + s; b1v[ct] = bn1[n]; b2v[ct] = bn2[n]; }

  f4 acc[2][4];
#pragma unroll
  for (int ct = 0; ct < 4; ++ct){ f4 t = {b1v[ct], b1v[ct], b1v[ct], b1v[ct]}; acc[0][ct] = t; acc[1][ct] = t; }

  bf8 a[2][8];
#pragma unroll
  for (int rt = 0; rt < 2; ++rt)
#pragma unroll
    for (int kk = 0; kk < 8; ++kk)
      a[rt][kk] = lds_frag(Ash, wr*32 + rt*16 + s, 512, kk*32 + g*8);
  __syncthreads();   // frag reads done -> Ash reusable as T

#pragma unroll
  for (int ct = 0; ct < 4; ++ct){
    int n = wc*64 + ct*16 + s;
#pragma unroll
    for (int kk = 0; kk < 8; ++kk){
      bf8 b = gfrag(Wn1T, n, 256, kk*32 + g*8);
      acc[0][ct] = MFMA16(a[0][kk], b, acc[0][ct]);
      acc[1][ct] = MFMA16(a[1][kk], b, acc[1][ct]);
    }
  }

#pragma unroll
  for (int rt = 0; rt < 2; ++rt)
#pragma unroll
    for (int ct = 0; ct < 4; ++ct)
#pragma unroll
      for (int reg = 0; reg < 4; ++reg)
        acc[rt][ct][reg] = mishf(acc[rt][ct][reg]);
  write_T((us*)Ash, wr, wc, g, s, acc);
  __syncthreads();

  f4 acc2[2][4];
#pragma unroll
  for (int ct = 0; ct < 4; ++ct){ f4 t = {b2v[ct], b2v[ct], b2v[ct], b2v[ct]}; acc2[0][ct] = t; acc2[1][ct] = t; }
  bf8 a2[2][4];
  load_a2((const us*)Ash, wr, g, s, a2);
#pragma unroll
  for (int ct = 0; ct < 4; ++ct){
    int n = wc*64 + ct*16 + s;
#pragma unroll
    for (int kk = 0; kk < 4; ++kk){
      bf8 b = gfrag(Wn2T, n, DN, kk*32 + g*8);
      acc2[0][ct] = MFMA16(a2[0][kk], b, acc2[0][ct]);
      acc2[1][ct] = MFMA16(a2[1][kk], b, acc2[1][ct]);
    }
  }
  store_tile<0>((void*)outh, NND, r0, wr, wc, g, s, DN, acc2);
}

struct WPrepArgs {
  const float* w[12];
  us* wt[12];
  int K[12];
};

// W^T bf16: wt[n*K + k] = bf16(W[k*128 + n])
__global__ void prep_weights(WPrepArgs a){
  int widx = blockIdx.y;
  int K = a.K[widx];
  int idx = blockIdx.x * 256 + threadIdx.x;
  if (idx >= DN * K) return;
  int kshift = (K == 256) ? 8 : 7;
  int n = idx >> kshift;
  int k = idx & (K - 1);
  a.wt[widx][idx] = f2bf(a.w[widx][(size_t)k * DN + n]);
}

extern "C" void kernel_launch(void* const* d_in, const int* in_sizes, int n_in,
                              void* d_out, int out_size, void* d_ws, size_t ws_size,
                              hipStream_t stream) {
  const float* node_feat = (const float*)d_in[0];
  const float* coordf    = (const float*)d_in[1];
  const float* Wq  = (const float*)d_in[2];
  const float* bq  = (const float*)d_in[3];
  const float* gq  = (const float*)d_in[4];
  const float* beq = (const float*)d_in[5];
  const float* Wk  = (const float*)d_in[6];
  const float* bk  = (const float*)d_in[7];
  const float* gk  = (const float*)d_in[8];
  const float* bek = (const float*)d_in[9];
  const float* Wm1 = (const float*)d_in[10];
  const float* bm1 = (const float*)d_in[11];
  const float* gm  = (const float*)d_in[12];
  const float* bem = (const float*)d_in[13];
  const float* Wm2 = (const float*)d_in[14];
  const float* bm2 = (const float*)d_in[15];
  const float* Wb1 = (const float*)d_in[16];
  const float* bb1 = (const float*)d_in[17];
  const float* gb  = (const float*)d_in[18];
  const float* beb = (const float*)d_in[19];
  const float* Wb2 = (const float*)d_in[20];
  const float* bb2 = (const float*)d_in[21];
  const float* Ww1 = (const float*)d_in[22];
  const float* bw1 = (const float*)d_in[23];
  const float* gw  = (const float*)d_in[24];
  const float* bew = (const float*)d_in[25];
  const float* Ww2 = (const float*)d_in[26];
  const float* bw2 = (const float*)d_in[27];
  const float* Wn1 = (const float*)d_in[28];
  const float* bn1 = (const float*)d_in[29];
  const float* Wn2 = (const float*)d_in[30];
  const float* bn2 = (const float*)d_in[31];
  const float* Wc1 = (const float*)d_in[32];
  const float* bc1 = (const float*)d_in[33];
  const float* Wc2 = (const float*)d_in[34];
  const int* srcI  = (const int*)d_in[35];
  const int* dstI  = (const int*)d_in[36];

  char* ws = (char*)d_ws;
  size_t off = 0;
  auto alloc = [&](size_t bytes) -> char* {
    char* p = ws + off;
    off += (bytes + 255) & ~(size_t)255;
    return p;
  };
  us*    qt       = (us*)alloc((size_t)NND * DN * 2);
  us*    kmb      = (us*)alloc((size_t)NND * 384 * 2);
  float* hacc     = (float*)alloc((size_t)NND * DN * 4);
  float* colsum16 = (float*)alloc(16 * DN * 4);
  int*   deg      = (int*)alloc((size_t)NND * 4);
  int*   fillctr  = (int*)alloc((size_t)NND * 4);
  int*   ssorted  = (int*)alloc((size_t)NED * 4);
  int*   dsorted  = (int*)alloc((size_t)NED * 4);
  int*   bsum     = (int*)alloc((size_t)NSCAN * 4);
  int*   boff     = (int*)alloc((size_t)NSCAN * 4);
  us*    wtb      = (us*)alloc((size_t)13 * 16384 * 2);   // 11 K=128 + 1 K=256 (2 slots)

  // zero the atomic accumulators (hacc + colsum16 are adjacent)
  hipMemsetAsync(hacc, 0, (size_t)NND * DN * 4 + 16 * DN * 4, stream);
  hipMemsetAsync(deg, 0, (size_t)NND * 4, stream);

  WPrepArgs pa;
  const float* wsrc[12] = {Wq, Wk, Wm1, Wm2, Wb1, Wb2, Ww1, Ww2, Wc1, Wc2, Wn2, Wn1};
  for (int i = 0; i < 12; ++i){
    pa.w[i] = wsrc[i];
    pa.wt[i] = wtb + (size_t)i * 16384;
    pa.K[i] = (i == 11) ? 256 : 128;
  }
  prep_weights<<<dim3(128, 12), 256, 0, stream>>>(pa);

  // CSR positions + edge sort by dst
  csr_count<<<(NED + 255) / 256, 256, 0, stream>>>(dstI, deg);
  csr_blocksum<<<NSCAN, 1024, 0, stream>>>(deg, bsum);
  csr_scanroot<<<1, 64, 0, stream>>>(bsum, boff);
  csr_scatter<<<NSCAN, 1024, 0, stream>>>(deg, boff, fillctr);
  csr_fill<<<(NED + 255) / 256, 256, 0, stream>>>(srcI, dstI, fillctr, ssorted, dsorted);

  const int NB = (NND + 63) / 64;  // 782

  node_fused<<<NB, 256, 0, stream>>>(coordf,
      pa.wt[0], bq, gq, beq,
      pa.wt[1], bk, gk, bek,
      pa.wt[2], bm1, gm, bem, pa.wt[3], bm2,
      pa.wt[4], bb1, gb, beb, pa.wt[5], bb2,
      pa.wt[8], bc1, pa.wt[9],
      qt, kmb, (float*)d_out + (size_t)NND * DN);

  edge_kernel<<<NED / 128, 256, 0, stream>>>(qt, kmb, pa.wt[6], pa.wt[7],
                                             bw1, gw, bew, bw2, ssorted, dsorted,
                                             hacc, colsum16);

  final_h<<<NB, 256, 0, stream>>>(node_feat, hacc, colsum16,
                                  pa.wt[11], bn1, pa.wt[10], bn2, (float*)d_out);
}